// Round 8
// baseline (249.510 us; speedup 1.0000x reference)
//
#include <hip/hip_runtime.h>
#include <cstdint>
#include <cstddef>

// FeatureAttention: x[4,2048,1024] fp32; Q=xWq^T+bq, K=xWk^T+bk, V=xWv^T+bv;
// out = softmax(QK^T/32) V.  bf16 MFMA pipeline.
//
// R12 = R11 (BK=32 issue-early double-buffer, 33KB LDS, 4 blocks/CU) with the
// bank swizzle corrected for the 64-byte row stride. R11's slot=(c+r)&3 put
// fg-group rows {0,4,8,12} in the same banks -> 4.19M conflicts/dispatch.
// Correct: slot=(c+(r>>1))&3. Rows 0-7 then start at banks
// {0,16,4,20,8,24,12,28} (complete 32-bank partition); rows 8-15 repeat =
// 2-way aliasing, which is free (m136).
//   prologue: stage(0); syncthreads
//   iter t:   stage(t+1) -> buf[(t+1)&1]   (issued FIRST, hidden under compute)
//             compute(t) from buf[t&1]
//             __syncthreads()
//   tail:     compute(NT-1)
//
// Workspace (80 MB):
//   [0,16M)  Xb    [16,20) Wqkb (Wq|Wk stacked)  [20,22) Wvb
//   [32,64M) QKb   [8192][2048]: Q cols 0-1023, K cols 1024-2047
//   [64,80M) Vt    (V transposed [1024][8192])
//   [0,32M)  Sc    (exp(scores) bf16 [4][2048][2048], reuses dead region)

typedef unsigned short ushort_t;
typedef __attribute__((ext_vector_type(8))) short short8;
typedef __attribute__((ext_vector_type(4))) float f32x4;

#define AS1 __attribute__((address_space(1)))
#define AS3 __attribute__((address_space(3)))

__device__ __forceinline__ ushort_t f2bf(float f) {
    unsigned int u = __float_as_uint(f);
    u += 0x7FFFu + ((u >> 16) & 1u);
    return (ushort_t)(u >> 16);
}
__device__ __forceinline__ float bf2f(ushort_t b) {
    return __uint_as_float(((unsigned)b) << 16);
}

// async global->LDS, 16B/lane; lds dest = wave-uniform base + lane*16
__device__ __forceinline__ void async_ld16(const void* g, unsigned lds_off) {
    __builtin_amdgcn_global_load_lds((const AS1 void*)(uintptr_t)g,
                                     (AS3 void*)(uintptr_t)lds_off,
                                     16, 0, 0);
}

// ---------------------------------------------------------------------------
// Double-buffered BT-GEMM, 128x128 tile, BK=32, 256 threads (4 waves 2x2).
//   C[m*ldc+n] = epi( scale * sum_k A[m*lda+k] * B[n*ldb+k] )
// EPI: 1 +bias(n): n<1024 ? bias0[n] : bias1[n-1024]
//      2 +bias0[m] | 3 exp(v) | 4 v / rowsum(A-tile row m) (in-kernel rowsum)
// Swizzle: 16B chunk c of row r stored at slot (c+(r>>1))&3 (applied on the
// staging *source* chunk; global_load_lds lane->LDS map is fixed).
// CX,CY: XCD chunk dims (bijective remap; NCX*NCY*NCZ must equal 8).
// ---------------------------------------------------------------------------
template <typename OT, int EPI, int CX, int CY>
__global__ __launch_bounds__(256, 4) void gemm_db(
    const ushort_t* __restrict__ A, const ushort_t* __restrict__ B,
    const float* __restrict__ bias0, const float* __restrict__ bias1,
    OT* __restrict__ C, int K, int lda, int ldb, int ldc, float scale,
    long long aOffZ, long long bOffZ, long long cOffZ)
{
    constexpr int BK = 32;

    __shared__ __align__(16) ushort_t As[2][128 * BK];
    __shared__ __align__(16) ushort_t Bs[2][128 * BK];
    __shared__ float rs[128];       // EPI==4 only

    const int tid  = threadIdx.x;
    const int wave = tid >> 6;
    const int lane = tid & 63;

    // ---- bijective XCD-chunked remap (XCD = linear%8) ----
    const int GX  = gridDim.x, GY = gridDim.y, GZ = gridDim.z;
    const int bid = blockIdx.x + GX * (blockIdx.y + GY * blockIdx.z);
    const int xcd = bid & 7;
    const int jj  = bid >> 3;
    const int CZ  = (GX * GY * GZ) / (8 * CX * CY);
    const int NCX = GX / CX, NCY = GY / CY;
    const int cx  = xcd % NCX;
    const int ct  = xcd / NCX;
    const int cy  = ct % NCY, cz = ct / NCY;
    const int bx  = cx * CX + (jj % CX);
    const int by  = cy * CY + ((jj / CX) % CY);
    const int bz  = cz * CZ + jj / (CX * CY);

    A += (size_t)bz * aOffZ;
    B += (size_t)bz * bOffZ;

    const int m0 = by * 128;
    const int n0 = bx * 128;
    const int wm = (wave >> 1) * 64;
    const int wn = (wave & 1) * 64;

    const unsigned aB0 = (unsigned)(uintptr_t)&As[0][0];
    const unsigned aB1 = (unsigned)(uintptr_t)&As[1][0];
    const unsigned bB0 = (unsigned)(uintptr_t)&Bs[0][0];
    const unsigned bB1 = (unsigned)(uintptr_t)&Bs[1][0];

    // staging map: 64 rows/call (16 rows/wave), 4 chunks of 16B per row
    // lane l writes LDS row (l>>2), slot (l&3); source chunk inverts swizzle
    const int srow = wave * 16 + (lane >> 2);
    const int cd   = ((lane & 3) - (srow >> 1)) & 3;   // swizzled source chunk
    const unsigned lw = (unsigned)(wave << 10);

    const ushort_t* gA = A + (size_t)(m0 + srow) * lda + cd * 8;
    const ushort_t* gB = B + (size_t)(n0 + srow) * ldb + cd * 8;

    // stage K-tile t into buf t&1 (4 calls: 2 A + 2 B)
    auto stage = [&](int t) {
        const int buf = t & 1;
        const ushort_t* pA = gA + (size_t)t * BK;
        const ushort_t* pB = gB + (size_t)t * BK;
        const unsigned la = (buf ? aB1 : aB0) + lw;
        const unsigned lb = (buf ? bB1 : bB0) + lw;
#pragma unroll
        for (int c = 0; c < 2; ++c) {
            async_ld16(pA + (size_t)(c * 64) * lda, la + c * 4096);
            async_ld16(pB + (size_t)(c * 64) * ldb, lb + c * 4096);
        }
    };

    // fragment map: lane -> row l&15; logical k-chunk fg at slot (fg+(r>>1))&3
    const int frow = lane & 15;
    const int fg   = lane >> 4;

    const int NT = K / BK;

    f32x4 acc[4][4] = {};
    float rsacc[4] = {0.f, 0.f, 0.f, 0.f};

    // one K-tile of compute from buffer `buf` (16 MFMA, 8 ds_read_b128)
    auto compute = [&](int buf) {
        const ushort_t* Aw = &As[buf][0];
        const ushort_t* Bw = &Bs[buf][0];
        const int pa = ((fg + (frow >> 1)) & 3) << 3;
        short8 af[4], bf[4];
#pragma unroll
        for (int i = 0; i < 4; ++i)
            af[i] = *(const short8*)&Aw[(wm + i * 16 + frow) * BK + pa];
        if (EPI == 4 && wn == 0) {   // rowsum of the streamed A tile
#pragma unroll
            for (int i = 0; i < 4; ++i)
#pragma unroll
                for (int e = 0; e < 8; ++e)
                    rsacc[i] += bf2f((ushort_t)af[i][e]);
        }
#pragma unroll
        for (int j = 0; j < 4; ++j)
            bf[j] = *(const short8*)&Bw[(wn + j * 16 + frow) * BK + pa];
#pragma unroll
        for (int i = 0; i < 4; ++i)
#pragma unroll
            for (int j = 0; j < 4; ++j)
                acc[i][j] = __builtin_amdgcn_mfma_f32_16x16x32_bf16(
                    af[i], bf[j], acc[i][j], 0, 0, 0);
    };

    // prologue: stage tile 0, full drain once
    stage(0);
    __syncthreads();

    for (int t = 0; t < NT - 1; ++t) {
        stage(t + 1);        // issued early: latency hidden under compute(t)
        compute(t & 1);
        __syncthreads();     // tile t+1 landed; all waves done with buf[t&1]
    }
    compute((NT - 1) & 1);   // tail

    if (EPI == 4) {
        if (wn == 0) {
#pragma unroll
            for (int i = 0; i < 4; ++i) {
                float s = rsacc[i];
                s += __shfl_xor(s, 16, 64);   // combine fg 0<->1
                s += __shfl_xor(s, 32, 64);   // combine fg pairs
                rs[wm + i * 16 + frow] = s;   // 4 lanes, same value/addr
            }
        }
        __syncthreads();
    }

    // C/D layout: lane l reg r -> row (l>>4)*4+r, col l&15
    C += (size_t)bz * cOffZ;
    const int r0 = fg << 2;
    const int c0 = lane & 15;
#pragma unroll
    for (int i = 0; i < 4; ++i) {
        float bm[4];
        if (EPI == 2) {
#pragma unroll
            for (int r = 0; r < 4; ++r)
                bm[r] = bias0[m0 + wm + i * 16 + r0 + r];
        }
        if (EPI == 4) {
#pragma unroll
            for (int r = 0; r < 4; ++r)
                bm[r] = 1.0f / rs[wm + i * 16 + r0 + r];
        }
#pragma unroll
        for (int j = 0; j < 4; ++j) {
            const int n = n0 + wn + j * 16 + c0;
            float bn = 0.f;
            if (EPI == 1) bn = (n < 1024) ? bias0[n] : bias1[n - 1024];
#pragma unroll
            for (int r = 0; r < 4; ++r) {
                const int m = m0 + wm + i * 16 + r0 + r;
                float v = acc[i][j][r] * scale;
                if (EPI == 1) v += bn;
                if (EPI == 2) v += bm[r];
                if (EPI == 3) v = __expf(v);
                if (EPI == 4) v *= bm[r];
                if constexpr (sizeof(OT) == 2)
                    C[(size_t)m * ldc + n] = f2bf(v);
                else
                    C[(size_t)m * ldc + n] = v;
            }
        }
    }
}

// one-shot fp32->bf16 cast of x, Wq, Wk, Wv (block-range dispatch)
__global__ __launch_bounds__(256) void cvt_all(
    const float* __restrict__ x,  const float* __restrict__ wq,
    const float* __restrict__ wk, const float* __restrict__ wv,
    ushort_t* __restrict__ xb,  ushort_t* __restrict__ wqb,
    ushort_t* __restrict__ wkb, ushort_t* __restrict__ wvb)
{
    const int b = blockIdx.x;
    const float* src; ushort_t* dst; size_t base;
    if (b < 4096)      { src = x;  dst = xb;  base = (size_t)b * 2048; }
    else if (b < 4608) { src = wq; dst = wqb; base = (size_t)(b - 4096) * 2048; }
    else if (b < 5120) { src = wk; dst = wkb; base = (size_t)(b - 4608) * 2048; }
    else               { src = wv; dst = wvb; base = (size_t)(b - 5120) * 2048; }
    const size_t i = base + threadIdx.x * 8;
    const f32x4 a = *(const f32x4*)(src + i);
    const f32x4 c = *(const f32x4*)(src + i + 4);
    short8 o;
    o[0] = (short)f2bf(a[0]); o[1] = (short)f2bf(a[1]);
    o[2] = (short)f2bf(a[2]); o[3] = (short)f2bf(a[3]);
    o[4] = (short)f2bf(c[0]); o[5] = (short)f2bf(c[1]);
    o[6] = (short)f2bf(c[2]); o[7] = (short)f2bf(c[3]);
    *(short8*)(dst + i) = o;
}

extern "C" void kernel_launch(void* const* d_in, const int* in_sizes, int n_in,
                              void* d_out, int out_size, void* d_ws, size_t ws_size,
                              hipStream_t stream)
{
    const float* x  = (const float*)d_in[0];
    const float* Wq = (const float*)d_in[1];
    const float* bq = (const float*)d_in[2];
    const float* Wk = (const float*)d_in[3];
    const float* bk = (const float*)d_in[4];
    const float* Wv = (const float*)d_in[5];
    const float* bv = (const float*)d_in[6];
    float* out = (float*)d_out;

    char* ws = (char*)d_ws;
    const size_t MB = 1ull << 20;
    ushort_t* Xb   = (ushort_t*)(ws);
    ushort_t* Wqkb = (ushort_t*)(ws + 16 * MB);  // Wq rows 0-1023 | Wk rows 1024-2047
    ushort_t* Wvb  = (ushort_t*)(ws + 20 * MB);
    ushort_t* QKb  = (ushort_t*)(ws + 32 * MB);  // [8192][2048]: Q | K
    ushort_t* Vt   = (ushort_t*)(ws + 64 * MB);  // [1024][8192]
    ushort_t* Sc   = (ushort_t*)(ws);            // reuses dead Xb/W region

    // 1) all casts in one launch (wq -> ws+16M, wk -> ws+18M: stacked Wqkb)
    cvt_all<<<dim3(5632), dim3(256), 0, stream>>>(
        x, Wq, Wk, Wv, Xb, Wqkb, (ushort_t*)(ws + 18 * MB), Wvb);

    // 2) QK projection: A=Xb [8192x1024], B=Wqkb [2048x1024] -> QKb [8192x2048]
    //    grid 16x64=1024; chunk 8x x 16y (A 4MB + B 2MB per XCD)
    gemm_db<ushort_t, 1, 8, 16><<<dim3(16, 64, 1), dim3(256), 0, stream>>>(
        Xb, Wqkb, bq, bk, QKb, 1024, 1024, 1024, 2048, 1.0f, 0, 0, 0);

    // 3) Vt = Wv X^T + bv(row)  [1024,8192]
    //    grid 64x8=512; chunk 16x x 4y (A 1MB + B 4MB per XCD)
    gemm_db<ushort_t, 2, 16, 4><<<dim3(64, 8, 1), dim3(256), 0, stream>>>(
        Wvb, Xb, bv, nullptr, Vt, 1024, 1024, 1024, 8192, 1.0f, 0, 0, 0);

    // 4) Sc = exp(Q K^T / 32) per batch (max-free softmax numerator)
    //    grid 16x16x4=1024; chunk 8x x 16y x 1z (Q 4MB + K 2MB per XCD)
    gemm_db<ushort_t, 3, 8, 16><<<dim3(16, 16, 4), dim3(256), 0, stream>>>(
        QKb, QKb + 1024, nullptr, nullptr, Sc, 1024, 2048, 2048, 2048,
        0.03125f, 2048ll * 2048, 2048ll * 2048, 2048ll * 2048);

    // 5) out = (Sc Vt^T) / rowsum(Sc row), rowsum fused in-kernel
    //    grid 8x16x4=512; chunk 8x x 8y x 1z (Sc 4MB + Vt 4MB per XCD)
    gemm_db<float, 4, 8, 8><<<dim3(8, 16, 4), dim3(256), 0, stream>>>(
        Sc, Vt, nullptr, nullptr, out, 2048, 2048, 8192, 1024, 1.0f,
        2048ll * 2048, 2048ll, 2048ll * 1024);
}

// Round 9
// 239.031 us; speedup vs baseline: 1.0438x; 1.0438x over previous
//
#include <hip/hip_runtime.h>
#include <cstdint>
#include <cstddef>

// FeatureAttention: x[4,2048,1024] fp32; Q=xWq^T+bq, K=xWk^T+bk, V=xWv^T+bv;
// out = softmax(QK^T/32) V.  bf16 MFMA pipeline.
//
// R13 = R10 (BK=64 issue-early double-buffer, 66KB LDS, proven 232us) with
// the K-loop manually unrolled by 2 so buffer indices are compile-time
// constants: all LDS fragment/staging addresses become loop-invariant and
// hoist out of the loop (R10 showed VALUBusy~=MfmaUtil ~28% — address
// recompute was eating a full pipe). R11/R12's BK=32 regressed (barrier
// frequency doubled, occupancy gain never materialized); reverted.
//   prologue: stage(0)->buf0; sync
//   pair:     stage(t+1)->buf1; compute(buf0); sync;
//             stage(t+2)->buf0; compute(buf1); sync;
//   tail:     stage(NT-1)->buf1; compute(buf0); sync; compute(buf1)
// (NT even for all four GEMMs: 16/16/16/32.)
//
// Swizzle (P=8, row stride 128B): 16B chunk c of row r stored at slot
// (c+r)&7, applied on the staging *source* chunk; conflict-free (R10: 0).
//
// Workspace (80 MB):
//   [0,16M)  Xb    [16,20) Wqkb (Wq|Wk stacked)  [20,22) Wvb
//   [32,64M) QKb   [8192][2048]: Q cols 0-1023, K cols 1024-2047
//   [64,80M) Vt    (V transposed [1024][8192])
//   [0,32M)  Sc    (exp(scores) bf16 [4][2048][2048], reuses dead region)

typedef unsigned short ushort_t;
typedef __attribute__((ext_vector_type(8))) short short8;
typedef __attribute__((ext_vector_type(4))) float f32x4;

#define AS1 __attribute__((address_space(1)))
#define AS3 __attribute__((address_space(3)))

__device__ __forceinline__ ushort_t f2bf(float f) {
    unsigned int u = __float_as_uint(f);
    u += 0x7FFFu + ((u >> 16) & 1u);
    return (ushort_t)(u >> 16);
}
__device__ __forceinline__ float bf2f(ushort_t b) {
    return __uint_as_float(((unsigned)b) << 16);
}

// async global->LDS, 16B/lane; lds dest = wave-uniform base + lane*16
__device__ __forceinline__ void async_ld16(const void* g, unsigned lds_off) {
    __builtin_amdgcn_global_load_lds((const AS1 void*)(uintptr_t)g,
                                     (AS3 void*)(uintptr_t)lds_off,
                                     16, 0, 0);
}

// ---------------------------------------------------------------------------
// Double-buffered BT-GEMM, 128x128 tile, BK=64, 256 threads (4 waves 2x2).
//   C[m*ldc+n] = epi( scale * sum_k A[m*lda+k] * B[n*ldb+k] )
// EPI: 1 +bias(n): n<1024 ? bias0[n] : bias1[n-1024]
//      2 +bias0[m] | 3 exp(v) | 4 v / rowsum(A-tile row m) (in-kernel rowsum)
// CX,CY: XCD chunk dims (bijective remap; NCX*NCY*NCZ must equal 8).
// ---------------------------------------------------------------------------
template <typename OT, int EPI, int CX, int CY>
__global__ __launch_bounds__(256, 2) void gemm_db(
    const ushort_t* __restrict__ A, const ushort_t* __restrict__ B,
    const float* __restrict__ bias0, const float* __restrict__ bias1,
    OT* __restrict__ C, int K, int lda, int ldb, int ldc, float scale,
    long long aOffZ, long long bOffZ, long long cOffZ)
{
    constexpr int BK = 64;
    constexpr int NCALL = 4;        // staging calls per 128-row tile (32 rows ea)

    __shared__ __align__(16) ushort_t As[2][128 * BK];
    __shared__ __align__(16) ushort_t Bs[2][128 * BK];
    __shared__ float rs[128];       // EPI==4 only

    const int tid  = threadIdx.x;
    const int wave = tid >> 6;
    const int lane = tid & 63;

    // ---- bijective XCD-chunked remap (XCD = linear%8) ----
    const int GX  = gridDim.x, GY = gridDim.y, GZ = gridDim.z;
    const int bid = blockIdx.x + GX * (blockIdx.y + GY * blockIdx.z);
    const int xcd = bid & 7;
    const int jj  = bid >> 3;
    const int CZ  = (GX * GY * GZ) / (8 * CX * CY);
    const int NCX = GX / CX, NCY = GY / CY;
    const int cx  = xcd % NCX;
    const int ct  = xcd / NCX;
    const int cy  = ct % NCY, cz = ct / NCY;
    const int bx  = cx * CX + (jj % CX);
    const int by  = cy * CY + ((jj / CX) % CY);
    const int bz  = cz * CZ + jj / (CX * CY);

    A += (size_t)bz * aOffZ;
    B += (size_t)bz * bOffZ;

    const int m0 = by * 128;
    const int n0 = bx * 128;
    const int wm = (wave >> 1) * 64;
    const int wn = (wave & 1) * 64;

    const unsigned lw  = (unsigned)(wave << 10);
    const unsigned aL0 = (unsigned)(uintptr_t)&As[0][0] + lw;
    const unsigned aL1 = (unsigned)(uintptr_t)&As[1][0] + lw;
    const unsigned bL0 = (unsigned)(uintptr_t)&Bs[0][0] + lw;
    const unsigned bL1 = (unsigned)(uintptr_t)&Bs[1][0] + lw;

    // staging map: 32 rows/call, 8 rows/wave; swizzled source chunk
    const int srow = wave * 8 + (lane >> 3);
    const int cd   = ((lane & 7) - srow) & 7;
    const ushort_t* gA = A + (size_t)(m0 + srow) * lda + cd * 8;
    const ushort_t* gB = B + (size_t)(n0 + srow) * ldb + cd * 8;

    // stage K-tile t into the buffer whose LDS bases are (la,lb)
    auto stageT = [&](int t, unsigned la, unsigned lb) {
        const ushort_t* pA = gA + (size_t)t * BK;
        const ushort_t* pB = gB + (size_t)t * BK;
#pragma unroll
        for (int c = 0; c < NCALL; ++c) {
            async_ld16(pA + (size_t)(c * 32) * lda, la + c * 4096);
            async_ld16(pB + (size_t)(c * 32) * ldb, lb + c * 4096);
        }
    };

    // fragment map: lane -> row l&15; chunk (t2*4 + l>>4) at swizzled pos
    const int frow = lane & 15;
    const int fg   = lane >> 4;

    const int NT = K / BK;          // even (16 or 32) for all call sites

    f32x4 acc[4][4] = {};
    float rsacc[4] = {0.f, 0.f, 0.f, 0.f};

    // one K-tile of compute from fixed buffer pointers (32 MFMA, 16 b128)
    auto computeT = [&](const ushort_t* Aw, const ushort_t* Bw) {
#pragma unroll
        for (int t2 = 0; t2 < 2; ++t2) {
            const int pa = (((t2 << 2) + fg + frow) & 7) << 3;
            short8 af[4], bf[4];
#pragma unroll
            for (int i = 0; i < 4; ++i)
                af[i] = *(const short8*)&Aw[(wm + i * 16 + frow) * BK + pa];
            if (EPI == 4 && wn == 0) {   // rowsum of the streamed A tile
#pragma unroll
                for (int i = 0; i < 4; ++i)
#pragma unroll
                    for (int e = 0; e < 8; ++e)
                        rsacc[i] += bf2f((ushort_t)af[i][e]);
            }
#pragma unroll
            for (int j = 0; j < 4; ++j)
                bf[j] = *(const short8*)&Bw[(wn + j * 16 + frow) * BK + pa];
#pragma unroll
            for (int i = 0; i < 4; ++i)
#pragma unroll
                for (int j = 0; j < 4; ++j)
                    acc[i][j] = __builtin_amdgcn_mfma_f32_16x16x32_bf16(
                        af[i], bf[j], acc[i][j], 0, 0, 0);
        }
    };

    const ushort_t* A0 = &As[0][0];
    const ushort_t* A1 = &As[1][0];
    const ushort_t* B0 = &Bs[0][0];
    const ushort_t* B1 = &Bs[1][0];

    // prologue: tile 0 -> buf0, full drain once
    stageT(0, aL0, bL0);
    __syncthreads();

    int t = 0;
    for (; t + 2 < NT; t += 2) {
        stageT(t + 1, aL1, bL1);   // issued early: hidden under compute
        computeT(A0, B0);
        __syncthreads();
        stageT(t + 2, aL0, bL0);
        computeT(A1, B1);
        __syncthreads();
    }
    // t == NT-2 here (NT even)
    stageT(NT - 1, aL1, bL1);
    computeT(A0, B0);
    __syncthreads();
    computeT(A1, B1);              // tail

    if (EPI == 4) {
        if (wn == 0) {
#pragma unroll
            for (int i = 0; i < 4; ++i) {
                float s = rsacc[i];
                s += __shfl_xor(s, 16, 64);
                s += __shfl_xor(s, 32, 64);
                rs[wm + i * 16 + frow] = s;   // 4 lanes, same value/addr
            }
        }
        __syncthreads();
    }

    // C/D layout: lane l reg r -> row (l>>4)*4+r, col l&15
    C += (size_t)bz * cOffZ;
    const int r0 = fg << 2;
    const int c0 = lane & 15;
#pragma unroll
    for (int i = 0; i < 4; ++i) {
        float bm[4];
        if (EPI == 2) {
#pragma unroll
            for (int r = 0; r < 4; ++r)
                bm[r] = bias0[m0 + wm + i * 16 + r0 + r];
        }
        if (EPI == 4) {
#pragma unroll
            for (int r = 0; r < 4; ++r)
                bm[r] = 1.0f / rs[wm + i * 16 + r0 + r];
        }
#pragma unroll
        for (int j = 0; j < 4; ++j) {
            const int n = n0 + wn + j * 16 + c0;
            float bn = 0.f;
            if (EPI == 1) bn = (n < 1024) ? bias0[n] : bias1[n - 1024];
#pragma unroll
            for (int r = 0; r < 4; ++r) {
                const int m = m0 + wm + i * 16 + r0 + r;
                float v = acc[i][j][r] * scale;
                if (EPI == 1) v += bn;
                if (EPI == 2) v += bm[r];
                if (EPI == 3) v = __expf(v);
                if (EPI == 4) v *= bm[r];
                if constexpr (sizeof(OT) == 2)
                    C[(size_t)m * ldc + n] = f2bf(v);
                else
                    C[(size_t)m * ldc + n] = v;
            }
        }
    }
}

// one-shot fp32->bf16 cast of x, Wq, Wk, Wv (block-range dispatch)
__global__ __launch_bounds__(256) void cvt_all(
    const float* __restrict__ x,  const float* __restrict__ wq,
    const float* __restrict__ wk, const float* __restrict__ wv,
    ushort_t* __restrict__ xb,  ushort_t* __restrict__ wqb,
    ushort_t* __restrict__ wkb, ushort_t* __restrict__ wvb)
{
    const int b = blockIdx.x;
    const float* src; ushort_t* dst; size_t base;
    if (b < 4096)      { src = x;  dst = xb;  base = (size_t)b * 2048; }
    else if (b < 4608) { src = wq; dst = wqb; base = (size_t)(b - 4096) * 2048; }
    else if (b < 5120) { src = wk; dst = wkb; base = (size_t)(b - 4608) * 2048; }
    else               { src = wv; dst = wvb; base = (size_t)(b - 5120) * 2048; }
    const size_t i = base + threadIdx.x * 8;
    const f32x4 a = *(const f32x4*)(src + i);
    const f32x4 c = *(const f32x4*)(src + i + 4);
    short8 o;
    o[0] = (short)f2bf(a[0]); o[1] = (short)f2bf(a[1]);
    o[2] = (short)f2bf(a[2]); o[3] = (short)f2bf(a[3]);
    o[4] = (short)f2bf(c[0]); o[5] = (short)f2bf(c[1]);
    o[6] = (short)f2bf(c[2]); o[7] = (short)f2bf(c[3]);
    *(short8*)(dst + i) = o;
}

extern "C" void kernel_launch(void* const* d_in, const int* in_sizes, int n_in,
                              void* d_out, int out_size, void* d_ws, size_t ws_size,
                              hipStream_t stream)
{
    const float* x  = (const float*)d_in[0];
    const float* Wq = (const float*)d_in[1];
    const float* bq = (const float*)d_in[2];
    const float* Wk = (const float*)d_in[3];
    const float* bk = (const float*)d_in[4];
    const float* Wv = (const float*)d_in[5];
    const float* bv = (const float*)d_in[6];
    float* out = (float*)d_out;

    char* ws = (char*)d_ws;
    const size_t MB = 1ull << 20;
    ushort_t* Xb   = (ushort_t*)(ws);
    ushort_t* Wqkb = (ushort_t*)(ws + 16 * MB);  // Wq rows 0-1023 | Wk rows 1024-2047
    ushort_t* Wvb  = (ushort_t*)(ws + 20 * MB);
    ushort_t* QKb  = (ushort_t*)(ws + 32 * MB);  // [8192][2048]: Q | K
    ushort_t* Vt   = (ushort_t*)(ws + 64 * MB);  // [1024][8192]
    ushort_t* Sc   = (ushort_t*)(ws);            // reuses dead Xb/W region

    // 1) all casts in one launch (wq -> ws+16M, wk -> ws+18M: stacked Wqkb)
    cvt_all<<<dim3(5632), dim3(256), 0, stream>>>(
        x, Wq, Wk, Wv, Xb, Wqkb, (ushort_t*)(ws + 18 * MB), Wvb);

    // 2) QK projection: A=Xb [8192x1024], B=Wqkb [2048x1024] -> QKb [8192x2048]
    //    grid 16x64=1024; chunk 8x x 16y (A 4MB + B 2MB per XCD)
    gemm_db<ushort_t, 1, 8, 16><<<dim3(16, 64, 1), dim3(256), 0, stream>>>(
        Xb, Wqkb, bq, bk, QKb, 1024, 1024, 1024, 2048, 1.0f, 0, 0, 0);

    // 3) Vt = Wv X^T + bv(row)  [1024,8192]
    //    grid 64x8=512; chunk 16x x 4y (A 1MB + B 4MB per XCD)
    gemm_db<ushort_t, 2, 16, 4><<<dim3(64, 8, 1), dim3(256), 0, stream>>>(
        Wvb, Xb, bv, nullptr, Vt, 1024, 1024, 1024, 8192, 1.0f, 0, 0, 0);

    // 4) Sc = exp(Q K^T / 32) per batch (max-free softmax numerator)
    //    grid 16x16x4=1024; chunk 8x x 16y x 1z (Q 4MB + K 2MB per XCD)
    gemm_db<ushort_t, 3, 8, 16><<<dim3(16, 16, 4), dim3(256), 0, stream>>>(
        QKb, QKb + 1024, nullptr, nullptr, Sc, 1024, 2048, 2048, 2048,
        0.03125f, 2048ll * 2048, 2048ll * 2048, 2048ll * 2048);

    // 5) out = (Sc Vt^T) / rowsum(Sc row), rowsum fused in-kernel
    //    grid 8x16x4=512; chunk 8x x 8y x 1z (Sc 4MB + Vt 4MB per XCD)
    gemm_db<float, 4, 8, 8><<<dim3(8, 16, 4), dim3(256), 0, stream>>>(
        Sc, Vt, nullptr, nullptr, out, 2048, 2048, 8192, 1024, 1.0f,
        2048ll * 2048, 2048ll, 2048ll * 1024);
}

// Round 10
// 235.304 us; speedup vs baseline: 1.0604x; 1.0158x over previous
//
#include <hip/hip_runtime.h>
#include <cstdint>
#include <cstddef>

// FeatureAttention: x[4,2048,1024] fp32; Q=xWq^T+bq, K=xWk^T+bk, V=xWv^T+bv;
// out = softmax(QK^T/32) V.  bf16 MFMA pipeline.
//
// R14 = R13 (BK=64 issue-early dbuf, unroll-2, XCD remap; GEMM core proven
// 45us/34GF) + two out-of-loop cuts:
//  (a) proj and Vt merged into ONE dispatch (block-role split at bid 1024):
//      Vt's 512 blocks pack into proj's round tail; one launch gap removed.
//  (b) PV rowsum via ones-MFMA: mfma(af, 1.0-frag) accumulates rowsum in
//      C/D layout (row = fg*4+r), replacing the 128-op VALU chain + shfl.
//
// Schedule per K-tile pair (NT even: 16/16/32):
//   stage(t+1)->buf1; compute(buf0); sync; stage(t+2)->buf0; compute(buf1); sync
// Swizzle (P=8): 16B chunk c of row r at slot (c+r)&7 on the staging source.
//
// Workspace (80 MB):
//   [0,16M)  Xb    [16,20) Wqkb (Wq|Wk stacked)  [20,22) Wvb
//   [32,64M) QKb   [8192][2048]: Q cols 0-1023, K cols 1024-2047
//   [64,80M) Vt    (V transposed [1024][8192])
//   [0,32M)  Sc    (exp(scores) bf16 [4][2048][2048], reuses dead region)

typedef unsigned short ushort_t;
typedef __attribute__((ext_vector_type(8))) short short8;
typedef __attribute__((ext_vector_type(4))) float f32x4;

#define AS1 __attribute__((address_space(1)))
#define AS3 __attribute__((address_space(3)))

__device__ __forceinline__ ushort_t f2bf(float f) {
    unsigned int u = __float_as_uint(f);
    u += 0x7FFFu + ((u >> 16) & 1u);
    return (ushort_t)(u >> 16);
}

// async global->LDS, 16B/lane; lds dest = wave-uniform base + lane*16
__device__ __forceinline__ void async_ld16(const void* g, unsigned lds_off) {
    __builtin_amdgcn_global_load_lds((const AS1 void*)(uintptr_t)g,
                                     (AS3 void*)(uintptr_t)lds_off,
                                     16, 0, 0);
}

// bijective XCD remap for a GX x GY grid (GZ=1), NCX*NCY must equal 8
__device__ __forceinline__ void remap2(int id, int GX, int GY, int CX, int CY,
                                       int& bx, int& by) {
    const int xcd = id & 7;
    const int jj  = id >> 3;
    const int NCX = GX / CX;
    const int cx  = xcd % NCX;
    const int cy  = xcd / NCX;
    bx = cx * CX + jj % CX;
    by = cy * CY + (jj / CX) % ((GY / CY) == 0 ? 1 : CY);
}

// ---------------------------------------------------------------------------
// gemm_db: double-buffered BT-GEMM, 128x128 tile, BK=64, 4 waves 2x2.
//   C[m*ldc+n] = epi( scale * sum_k A[m*lda+k] * B[n*ldb+k] )
// EPI: 3 exp(v) | 4 v / rowsum(A row) (rowsum via ones-MFMA)
// CX,CY: XCD chunk dims (NCX*NCY*NCZ == 8).
// ---------------------------------------------------------------------------
template <typename OT, int EPI, int CX, int CY>
__global__ __launch_bounds__(256, 2) void gemm_db(
    const ushort_t* __restrict__ A, const ushort_t* __restrict__ B,
    OT* __restrict__ C, int K, int lda, int ldb, int ldc, float scale,
    long long aOffZ, long long bOffZ, long long cOffZ)
{
    constexpr int BK = 64;
    constexpr int NCALL = 4;

    __shared__ __align__(16) ushort_t As[2][128 * BK];
    __shared__ __align__(16) ushort_t Bs[2][128 * BK];
    __shared__ float rs[128];       // EPI==4 only

    const int tid  = threadIdx.x;
    const int wave = tid >> 6;
    const int lane = tid & 63;

    // ---- bijective XCD-chunked remap (XCD = linear%8), 3D ----
    const int GX  = gridDim.x, GY = gridDim.y, GZ = gridDim.z;
    const int bid = blockIdx.x + GX * (blockIdx.y + GY * blockIdx.z);
    const int xcd = bid & 7;
    const int jj  = bid >> 3;
    const int CZ  = (GX * GY * GZ) / (8 * CX * CY);
    const int NCX = GX / CX, NCY = GY / CY;
    const int cx  = xcd % NCX;
    const int ct  = xcd / NCX;
    const int cy  = ct % NCY, cz = ct / NCY;
    const int bx  = cx * CX + (jj % CX);
    const int by  = cy * CY + ((jj / CX) % CY);
    const int bz  = cz * CZ + jj / (CX * CY);

    A += (size_t)bz * aOffZ;
    B += (size_t)bz * bOffZ;

    const int m0 = by * 128;
    const int n0 = bx * 128;
    const int wm = (wave >> 1) * 64;
    const int wn = (wave & 1) * 64;

    const unsigned lw  = (unsigned)(wave << 10);
    const unsigned aL0 = (unsigned)(uintptr_t)&As[0][0] + lw;
    const unsigned aL1 = (unsigned)(uintptr_t)&As[1][0] + lw;
    const unsigned bL0 = (unsigned)(uintptr_t)&Bs[0][0] + lw;
    const unsigned bL1 = (unsigned)(uintptr_t)&Bs[1][0] + lw;

    const int srow = wave * 8 + (lane >> 3);
    const int cd   = ((lane & 7) - srow) & 7;
    const ushort_t* gA = A + (size_t)(m0 + srow) * lda + cd * 8;
    const ushort_t* gB = B + (size_t)(n0 + srow) * ldb + cd * 8;

    auto stageT = [&](int t, unsigned la, unsigned lb) {
        const ushort_t* pA = gA + (size_t)t * BK;
        const ushort_t* pB = gB + (size_t)t * BK;
#pragma unroll
        for (int c = 0; c < NCALL; ++c) {
            async_ld16(pA + (size_t)(c * 32) * lda, la + c * 4096);
            async_ld16(pB + (size_t)(c * 32) * ldb, lb + c * 4096);
        }
    };

    const int frow = lane & 15;
    const int fg   = lane >> 4;

    const int NT = K / BK;          // even for all call sites

    f32x4 acc[4][4] = {};
    f32x4 rsm[4] = {};              // EPI==4: rowsum accumulators (ones-MFMA)
    const short8 ones = { (short)0x3F80, (short)0x3F80, (short)0x3F80,
                          (short)0x3F80, (short)0x3F80, (short)0x3F80,
                          (short)0x3F80, (short)0x3F80 };

    auto computeT = [&](const ushort_t* Aw, const ushort_t* Bw) {
#pragma unroll
        for (int t2 = 0; t2 < 2; ++t2) {
            const int pa = (((t2 << 2) + fg + frow) & 7) << 3;
            short8 af[4], bf[4];
#pragma unroll
            for (int i = 0; i < 4; ++i)
                af[i] = *(const short8*)&Aw[(wm + i * 16 + frow) * BK + pa];
            if (EPI == 4 && wn == 0) {   // rowsum via matrix pipe
#pragma unroll
                for (int i = 0; i < 4; ++i)
                    rsm[i] = __builtin_amdgcn_mfma_f32_16x16x32_bf16(
                        af[i], ones, rsm[i], 0, 0, 0);
            }
#pragma unroll
            for (int j = 0; j < 4; ++j)
                bf[j] = *(const short8*)&Bw[(wn + j * 16 + frow) * BK + pa];
#pragma unroll
            for (int i = 0; i < 4; ++i)
#pragma unroll
                for (int j = 0; j < 4; ++j)
                    acc[i][j] = __builtin_amdgcn_mfma_f32_16x16x32_bf16(
                        af[i], bf[j], acc[i][j], 0, 0, 0);
        }
    };

    const ushort_t* A0 = &As[0][0];
    const ushort_t* A1 = &As[1][0];
    const ushort_t* B0 = &Bs[0][0];
    const ushort_t* B1 = &Bs[1][0];

    stageT(0, aL0, bL0);
    __syncthreads();

    int t = 0;
    for (; t + 2 < NT; t += 2) {
        stageT(t + 1, aL1, bL1);
        computeT(A0, B0);
        __syncthreads();
        stageT(t + 2, aL0, bL0);
        computeT(A1, B1);
        __syncthreads();
    }
    stageT(NT - 1, aL1, bL1);
    computeT(A0, B0);
    __syncthreads();
    computeT(A1, B1);

    const int r0 = fg << 2;
    const int c0 = lane & 15;

    if (EPI == 4) {
        if (wn == 0 && c0 == 0) {   // lanes 0,16,32,48: rows r0+r of block i
#pragma unroll
            for (int i = 0; i < 4; ++i)
#pragma unroll
                for (int r = 0; r < 4; ++r)
                    rs[wm + i * 16 + r0 + r] = rsm[i][r];
        }
        __syncthreads();
    }

    // C/D layout: lane l reg r -> row (l>>4)*4+r, col l&15
    C += (size_t)bz * cOffZ;
#pragma unroll
    for (int i = 0; i < 4; ++i) {
        float bm[4];
        if (EPI == 4) {
#pragma unroll
            for (int r = 0; r < 4; ++r)
                bm[r] = 1.0f / rs[wm + i * 16 + r0 + r];
        }
#pragma unroll
        for (int j = 0; j < 4; ++j) {
            const int n = n0 + wn + j * 16 + c0;
#pragma unroll
            for (int r = 0; r < 4; ++r) {
                const int m = m0 + wm + i * 16 + r0 + r;
                float v = acc[i][j][r] * scale;
                if (EPI == 3) v = __expf(v);
                if (EPI == 4) v *= bm[r];
                if constexpr (sizeof(OT) == 2)
                    C[(size_t)m * ldc + n] = f2bf(v);
                else
                    C[(size_t)m * ldc + n] = v;
            }
        }
    }
}

// ---------------------------------------------------------------------------
// gemm_mrg: merged proj (blocks 0..1023) + Vt (blocks 1024..1535) dispatch.
//   proj: QKb[m][n] = Xb[m]·Wqkb[n] + (n<1024 ? bq[n] : bk[n-1024])
//   Vt:   Vt[m][n]  = Wvb[m]·Xb[n] + bv[m]
// Both K=1024, lda=ldb=1024, NT=16. Same proven loop body.
// ---------------------------------------------------------------------------
__global__ __launch_bounds__(256, 2) void gemm_mrg(
    const ushort_t* __restrict__ Xb, const ushort_t* __restrict__ Wqkb,
    const ushort_t* __restrict__ Wvb,
    const float* __restrict__ bq, const float* __restrict__ bk,
    const float* __restrict__ bv,
    ushort_t* __restrict__ QKb, ushort_t* __restrict__ Vtp)
{
    constexpr int BK = 64;
    constexpr int NCALL = 4;

    __shared__ __align__(16) ushort_t As[2][128 * BK];
    __shared__ __align__(16) ushort_t Bs[2][128 * BK];

    const int tid  = threadIdx.x;
    const int wave = tid >> 6;
    const int lane = tid & 63;

    const bool vtR = (blockIdx.x >= 1024);
    const int  id  = vtR ? (int)blockIdx.x - 1024 : (int)blockIdx.x;

    int bx, by;
    if (!vtR) {   // grid 16x64, chunk 8x x 16y (NCX=2, NCY=4)
        const int xcd = id & 7, jj = id >> 3;
        bx = (xcd % 2) * 8  + (jj % 8);
        by = (xcd / 2) * 16 + (jj / 8);
    } else {      // grid 64x8, chunk 16x x 4y (NCX=4, NCY=2)
        const int xcd = id & 7, jj = id >> 3;
        bx = (xcd % 4) * 16 + (jj % 16);
        by = (xcd / 4) * 4  + (jj / 16);
    }

    const ushort_t* A = vtR ? Wvb : Xb;
    const ushort_t* B = vtR ? Xb  : Wqkb;
    ushort_t*       C = vtR ? Vtp : QKb;
    const int ldc = vtR ? 8192 : 2048;

    const int m0 = by * 128;
    const int n0 = bx * 128;
    const int wm = (wave >> 1) * 64;
    const int wn = (wave & 1) * 64;

    const unsigned lw  = (unsigned)(wave << 10);
    const unsigned aL0 = (unsigned)(uintptr_t)&As[0][0] + lw;
    const unsigned aL1 = (unsigned)(uintptr_t)&As[1][0] + lw;
    const unsigned bL0 = (unsigned)(uintptr_t)&Bs[0][0] + lw;
    const unsigned bL1 = (unsigned)(uintptr_t)&Bs[1][0] + lw;

    const int srow = wave * 8 + (lane >> 3);
    const int cd   = ((lane & 7) - srow) & 7;
    const ushort_t* gA = A + (size_t)(m0 + srow) * 1024 + cd * 8;
    const ushort_t* gB = B + (size_t)(n0 + srow) * 1024 + cd * 8;

    auto stageT = [&](int t, unsigned la, unsigned lb) {
        const ushort_t* pA = gA + (size_t)t * BK;
        const ushort_t* pB = gB + (size_t)t * BK;
#pragma unroll
        for (int c = 0; c < NCALL; ++c) {
            async_ld16(pA + (size_t)(c * 32) * 1024, la + c * 4096);
            async_ld16(pB + (size_t)(c * 32) * 1024, lb + c * 4096);
        }
    };

    const int frow = lane & 15;
    const int fg   = lane >> 4;

    f32x4 acc[4][4] = {};

    auto computeT = [&](const ushort_t* Aw, const ushort_t* Bw) {
#pragma unroll
        for (int t2 = 0; t2 < 2; ++t2) {
            const int pa = (((t2 << 2) + fg + frow) & 7) << 3;
            short8 af[4], bf[4];
#pragma unroll
            for (int i = 0; i < 4; ++i)
                af[i] = *(const short8*)&Aw[(wm + i * 16 + frow) * BK + pa];
#pragma unroll
            for (int j = 0; j < 4; ++j)
                bf[j] = *(const short8*)&Bw[(wn + j * 16 + frow) * BK + pa];
#pragma unroll
            for (int i = 0; i < 4; ++i)
#pragma unroll
                for (int j = 0; j < 4; ++j)
                    acc[i][j] = __builtin_amdgcn_mfma_f32_16x16x32_bf16(
                        af[i], bf[j], acc[i][j], 0, 0, 0);
        }
    };

    const ushort_t* A0 = &As[0][0];
    const ushort_t* A1 = &As[1][0];
    const ushort_t* B0 = &Bs[0][0];
    const ushort_t* B1 = &Bs[1][0];

    stageT(0, aL0, bL0);
    __syncthreads();

    int t = 0;
    for (; t + 2 < 16; t += 2) {
        stageT(t + 1, aL1, bL1);
        computeT(A0, B0);
        __syncthreads();
        stageT(t + 2, aL0, bL0);
        computeT(A1, B1);
        __syncthreads();
    }
    stageT(15, aL1, bL1);
    computeT(A0, B0);
    __syncthreads();
    computeT(A1, B1);

    // epilogue
    const int r0 = fg << 2;
    const int c0 = lane & 15;
#pragma unroll
    for (int i = 0; i < 4; ++i) {
        float bm[4];
        if (vtR) {
#pragma unroll
            for (int r = 0; r < 4; ++r)
                bm[r] = bv[m0 + wm + i * 16 + r0 + r];
        }
#pragma unroll
        for (int j = 0; j < 4; ++j) {
            const int n = n0 + wn + j * 16 + c0;
            float bn = 0.f;
            if (!vtR) bn = (n < 1024) ? bq[n] : bk[n - 1024];
#pragma unroll
            for (int r = 0; r < 4; ++r) {
                const int m = m0 + wm + i * 16 + r0 + r;
                float v = acc[i][j][r] + (vtR ? bm[r] : bn);
                C[(size_t)m * ldc + n] = f2bf(v);
            }
        }
    }
}

// one-shot fp32->bf16 cast of x, Wq, Wk, Wv (block-range dispatch)
__global__ __launch_bounds__(256) void cvt_all(
    const float* __restrict__ x,  const float* __restrict__ wq,
    const float* __restrict__ wk, const float* __restrict__ wv,
    ushort_t* __restrict__ xb,  ushort_t* __restrict__ wqb,
    ushort_t* __restrict__ wkb, ushort_t* __restrict__ wvb)
{
    const int b = blockIdx.x;
    const float* src; ushort_t* dst; size_t base;
    if (b < 4096)      { src = x;  dst = xb;  base = (size_t)b * 2048; }
    else if (b < 4608) { src = wq; dst = wqb; base = (size_t)(b - 4096) * 2048; }
    else if (b < 5120) { src = wk; dst = wkb; base = (size_t)(b - 4608) * 2048; }
    else               { src = wv; dst = wvb; base = (size_t)(b - 5120) * 2048; }
    const size_t i = base + threadIdx.x * 8;
    const f32x4 a = *(const f32x4*)(src + i);
    const f32x4 c = *(const f32x4*)(src + i + 4);
    short8 o;
    o[0] = (short)f2bf(a[0]); o[1] = (short)f2bf(a[1]);
    o[2] = (short)f2bf(a[2]); o[3] = (short)f2bf(a[3]);
    o[4] = (short)f2bf(c[0]); o[5] = (short)f2bf(c[1]);
    o[6] = (short)f2bf(c[2]); o[7] = (short)f2bf(c[3]);
    *(short8*)(dst + i) = o;
}

extern "C" void kernel_launch(void* const* d_in, const int* in_sizes, int n_in,
                              void* d_out, int out_size, void* d_ws, size_t ws_size,
                              hipStream_t stream)
{
    const float* x  = (const float*)d_in[0];
    const float* Wq = (const float*)d_in[1];
    const float* bq = (const float*)d_in[2];
    const float* Wk = (const float*)d_in[3];
    const float* bk = (const float*)d_in[4];
    const float* Wv = (const float*)d_in[5];
    const float* bv = (const float*)d_in[6];
    float* out = (float*)d_out;

    char* ws = (char*)d_ws;
    const size_t MB = 1ull << 20;
    ushort_t* Xb   = (ushort_t*)(ws);
    ushort_t* Wqkb = (ushort_t*)(ws + 16 * MB);  // Wq rows 0-1023 | Wk rows 1024-2047
    ushort_t* Wvb  = (ushort_t*)(ws + 20 * MB);
    ushort_t* QKb  = (ushort_t*)(ws + 32 * MB);  // [8192][2048]: Q | K
    ushort_t* Vt   = (ushort_t*)(ws + 64 * MB);  // [1024][8192]
    ushort_t* Sc   = (ushort_t*)(ws);            // reuses dead Xb/W region

    // 1) all casts in one launch (wq -> ws+16M, wk -> ws+18M: stacked Wqkb)
    cvt_all<<<dim3(5632), dim3(256), 0, stream>>>(
        x, Wq, Wk, Wv, Xb, Wqkb, (ushort_t*)(ws + 18 * MB), Wvb);

    // 2) merged proj (1024 blocks) + Vt (512 blocks): one dispatch
    gemm_mrg<<<dim3(1536), dim3(256), 0, stream>>>(
        Xb, Wqkb, Wvb, bq, bk, bv, QKb, Vt);

    // 3) Sc = exp(Q K^T / 32) per batch (max-free softmax numerator)
    //    grid 16x16x4=1024; chunk 8x x 16y x 1z
    gemm_db<ushort_t, 3, 8, 16><<<dim3(16, 16, 4), dim3(256), 0, stream>>>(
        QKb, QKb + 1024, Sc, 1024, 2048, 2048, 2048,
        0.03125f, 2048ll * 2048, 2048ll * 2048, 2048ll * 2048);

    // 4) out = (Sc Vt^T) / rowsum(Sc row), rowsum via ones-MFMA
    //    grid 8x16x4=512; chunk 8x x 8y x 1z
    gemm_db<float, 4, 8, 8><<<dim3(8, 16, 4), dim3(256), 0, stream>>>(
        Sc, Vt, out, 2048, 2048, 8192, 1024, 1.0f,
        2048ll * 2048, 2048ll, 2048ll * 1024);
}

// Round 11
// 218.863 us; speedup vs baseline: 1.1400x; 1.0751x over previous
//
#include <hip/hip_runtime.h>
#include <hip/hip_cooperative_groups.h>
#include <cstdint>
#include <cstddef>

namespace cg = cooperative_groups;

// FeatureAttention: x[4,2048,1024] fp32; Q=xWq^T+bq, K=xWk^T+bk, V=xWv^T+bv;
// out = softmax(QK^T/32) V.  bf16 MFMA pipeline.
//
// R15: ONE cooperative mega-kernel (512 blocks = 2/CU, grid.sync between
// phases) eliminating the ~60us of inter-dispatch time R14 exposed
// (sum-of-kernels 172us vs wall 235us). Phases (grid-strided units of the
// proven R10/R14 128x128 BK=64 issue-early double-buffered GEMM body):
//   ph0 cast (5632 units, 11/block)   ph1 proj+Vt (1536, 3/block)
//   ph2 scores exp (1024, 2/block)    ph3 PV+rowsum-divide (512, 1/block)
// Fallback (occupancy<2 or coop-launch error): R14's 4-dispatch path with
// the identical unit body.
//
// Workspace (80 MB):
//   [0,16M)  Xb    [16,20) Wqkb (Wq|Wk stacked)  [20,22) Wvb
//   [32,64M) QKb   [8192][2048]: Q cols 0-1023, K cols 1024-2047
//   [64,80M) Vt    (V transposed [1024][8192])
//   [0,32M)  Sc    (exp(scores) bf16, reuses dead region after ph1)

typedef unsigned short ushort_t;
typedef __attribute__((ext_vector_type(8))) short short8;
typedef __attribute__((ext_vector_type(4))) float f32x4;

#define AS1 __attribute__((address_space(1)))
#define AS3 __attribute__((address_space(3)))

__device__ __forceinline__ ushort_t f2bf(float f) {
    unsigned int u = __float_as_uint(f);
    u += 0x7FFFu + ((u >> 16) & 1u);
    return (ushort_t)(u >> 16);
}

// async global->LDS, 16B/lane; lds dest = wave-uniform base + lane*16
__device__ __forceinline__ void async_ld16(const void* g, unsigned lds_off) {
    __builtin_amdgcn_global_load_lds((const AS1 void*)(uintptr_t)g,
                                     (AS3 void*)(uintptr_t)lds_off,
                                     16, 0, 0);
}

// bijective XCD-chunked remap (XCD = id%8), compile-time geometry
template <int GX, int GY, int GZ, int CX, int CY>
__device__ __forceinline__ void remapC(int id, int& bx, int& by, int& bz) {
    constexpr int CZ  = (GX * GY * GZ) / (8 * CX * CY);
    constexpr int NCX = GX / CX, NCY = GY / CY;
    const int xcd = id & 7, jj = id >> 3;
    const int cx = xcd % NCX, ct = xcd / NCX;
    const int cy = ct % NCY, cz = ct / NCY;
    bx = cx * CX + (jj % CX);
    by = cy * CY + ((jj / CX) % CY);
    bz = cz * CZ + jj / (CX * CY);
}

// ---------------------------------------------------------------------------
// gemm_unit: one 128x128 output tile, BK=64 issue-early double-buffer,
// 4 waves 2x2.  C[m*ldc+n] = epi( scale * sum_k A[m*lda+k] * B[n*ldb+k] )
// EPI: 1 +bias(n): n<1024 ? b0[n] : b1[n-1024] | 2 +b0[m] | 3 exp(v)
//      4 v / rowsum(A row)  (rowsum via ones-MFMA, C/D row layout)
// Swizzle (P=8): 16B chunk c of row r at slot (c+r)&7 on the staging source.
// ---------------------------------------------------------------------------
template <typename OT, int EPI>
__device__ __forceinline__ void gemm_unit(
    ushort_t (&As)[2][8192], ushort_t (&Bs)[2][8192], float (&rs)[128],
    const ushort_t* __restrict__ A, const ushort_t* __restrict__ B,
    const float* __restrict__ b0, const float* __restrict__ b1,
    OT* __restrict__ C, int NT, int lda, int ldb, int ldc, float scale,
    int m0, int n0)
{
    constexpr int BK = 64;
    const int tid  = threadIdx.x;
    const int wave = tid >> 6;
    const int lane = tid & 63;
    const int wm = (wave >> 1) * 64;
    const int wn = (wave & 1) * 64;

    const unsigned lw  = (unsigned)(wave << 10);
    const unsigned aL0 = (unsigned)(uintptr_t)&As[0][0] + lw;
    const unsigned aL1 = (unsigned)(uintptr_t)&As[1][0] + lw;
    const unsigned bL0 = (unsigned)(uintptr_t)&Bs[0][0] + lw;
    const unsigned bL1 = (unsigned)(uintptr_t)&Bs[1][0] + lw;

    const int srow = wave * 8 + (lane >> 3);
    const int cd   = ((lane & 7) - srow) & 7;
    const ushort_t* gA = A + (size_t)(m0 + srow) * lda + cd * 8;
    const ushort_t* gB = B + (size_t)(n0 + srow) * ldb + cd * 8;

    auto stageT = [&](int t, unsigned la, unsigned lb) {
        const ushort_t* pA = gA + (size_t)t * BK;
        const ushort_t* pB = gB + (size_t)t * BK;
#pragma unroll
        for (int c = 0; c < 4; ++c) {
            async_ld16(pA + (size_t)(c * 32) * lda, la + c * 4096);
            async_ld16(pB + (size_t)(c * 32) * ldb, lb + c * 4096);
        }
    };

    const int frow = lane & 15;
    const int fg   = lane >> 4;

    f32x4 acc[4][4] = {};
    f32x4 rsm[4] = {};
    const short8 ones = { (short)0x3F80, (short)0x3F80, (short)0x3F80,
                          (short)0x3F80, (short)0x3F80, (short)0x3F80,
                          (short)0x3F80, (short)0x3F80 };

    auto computeT = [&](const ushort_t* Aw, const ushort_t* Bw) {
#pragma unroll
        for (int t2 = 0; t2 < 2; ++t2) {
            const int pa = (((t2 << 2) + fg + frow) & 7) << 3;
            short8 af[4], bf[4];
#pragma unroll
            for (int i = 0; i < 4; ++i)
                af[i] = *(const short8*)&Aw[(wm + i * 16 + frow) * BK + pa];
            if (EPI == 4 && wn == 0) {   // rowsum via matrix pipe
#pragma unroll
                for (int i = 0; i < 4; ++i)
                    rsm[i] = __builtin_amdgcn_mfma_f32_16x16x32_bf16(
                        af[i], ones, rsm[i], 0, 0, 0);
            }
#pragma unroll
            for (int j = 0; j < 4; ++j)
                bf[j] = *(const short8*)&Bw[(wn + j * 16 + frow) * BK + pa];
#pragma unroll
            for (int i = 0; i < 4; ++i)
#pragma unroll
                for (int j = 0; j < 4; ++j)
                    acc[i][j] = __builtin_amdgcn_mfma_f32_16x16x32_bf16(
                        af[i], bf[j], acc[i][j], 0, 0, 0);
        }
    };

    const ushort_t* A0 = &As[0][0];
    const ushort_t* A1 = &As[1][0];
    const ushort_t* B0 = &Bs[0][0];
    const ushort_t* B1 = &Bs[1][0];

    stageT(0, aL0, bL0);
    __syncthreads();

    int t = 0;
    for (; t + 2 < NT; t += 2) {
        stageT(t + 1, aL1, bL1);   // issued early: hidden under compute
        computeT(A0, B0);
        __syncthreads();
        stageT(t + 2, aL0, bL0);
        computeT(A1, B1);
        __syncthreads();
    }
    stageT(NT - 1, aL1, bL1);
    computeT(A0, B0);
    __syncthreads();
    computeT(A1, B1);

    const int r0 = fg << 2;
    const int c0 = lane & 15;

    if (EPI == 4) {
        if (wn == 0 && c0 == 0) {   // lanes 0,16,32,48 hold rows r0..r0+3
#pragma unroll
            for (int i = 0; i < 4; ++i)
#pragma unroll
                for (int r = 0; r < 4; ++r)
                    rs[wm + i * 16 + r0 + r] = rsm[i][r];
        }
        __syncthreads();
    }

    // C/D layout: lane l reg r -> row (l>>4)*4+r, col l&15
#pragma unroll
    for (int i = 0; i < 4; ++i) {
        float bm[4];
        if (EPI == 2) {
#pragma unroll
            for (int r = 0; r < 4; ++r)
                bm[r] = b0[m0 + wm + i * 16 + r0 + r];
        }
        if (EPI == 4) {
#pragma unroll
            for (int r = 0; r < 4; ++r)
                bm[r] = 1.0f / rs[wm + i * 16 + r0 + r];
        }
#pragma unroll
        for (int j = 0; j < 4; ++j) {
            const int n = n0 + wn + j * 16 + c0;
            float bn = 0.f;
            if (EPI == 1) bn = (n < 1024) ? b0[n] : b1[n - 1024];
#pragma unroll
            for (int r = 0; r < 4; ++r) {
                const int m = m0 + wm + i * 16 + r0 + r;
                float v = acc[i][j][r] * scale;
                if (EPI == 1) v += bn;
                if (EPI == 2) v += bm[r];
                if (EPI == 3) v = __expf(v);
                if (EPI == 4) v *= bm[r];
                if constexpr (sizeof(OT) == 2)
                    C[(size_t)m * ldc + n] = f2bf(v);
                else
                    C[(size_t)m * ldc + n] = v;
            }
        }
    }
    // NOTE: no trailing barrier needed: next unit's stage(0,buf0) only
    // overwrites buf0, whose last reads precede the final in-loop barrier;
    // buf1's overwrite (stage(1)) is after the next unit's post-stage(0)
    // __syncthreads().
}

// cast unit u: 2048 fp32 -> bf16 (256 threads x 8)
__device__ __forceinline__ void cast_unit(
    int u, const float* x, const float* Wq, const float* Wk, const float* Wv,
    ushort_t* Xb, ushort_t* Wqkb, ushort_t* Wkb, ushort_t* Wvb)
{
    const float* src; ushort_t* dst; size_t base;
    if (u < 4096)      { src = x;  dst = Xb;   base = (size_t)u * 2048; }
    else if (u < 4608) { src = Wq; dst = Wqkb; base = (size_t)(u - 4096) * 2048; }
    else if (u < 5120) { src = Wk; dst = Wkb;  base = (size_t)(u - 4608) * 2048; }
    else               { src = Wv; dst = Wvb;  base = (size_t)(u - 5120) * 2048; }
    const size_t i = base + threadIdx.x * 8;
    const f32x4 a = *(const f32x4*)(src + i);
    const f32x4 c = *(const f32x4*)(src + i + 4);
    short8 o;
    o[0] = (short)f2bf(a[0]); o[1] = (short)f2bf(a[1]);
    o[2] = (short)f2bf(a[2]); o[3] = (short)f2bf(a[3]);
    o[4] = (short)f2bf(c[0]); o[5] = (short)f2bf(c[1]);
    o[6] = (short)f2bf(c[2]); o[7] = (short)f2bf(c[3]);
    *(short8*)(dst + i) = o;
}

// ---------------------------------------------------------------------------
// mega: the whole op in one cooperative kernel.
// ---------------------------------------------------------------------------
__global__ __launch_bounds__(256, 2) void mega(
    const float* __restrict__ x,
    const float* __restrict__ Wq, const float* __restrict__ bq,
    const float* __restrict__ Wk, const float* __restrict__ bk,
    const float* __restrict__ Wv, const float* __restrict__ bv,
    float* __restrict__ out, char* __restrict__ ws)
{
    __shared__ __align__(16) ushort_t As[2][8192];
    __shared__ __align__(16) ushort_t Bs[2][8192];
    __shared__ float rs[128];

    const size_t MB = 1ull << 20;
    ushort_t* Xb   = (ushort_t*)(ws);
    ushort_t* Wqkb = (ushort_t*)(ws + 16 * MB);
    ushort_t* Wkb  = (ushort_t*)(ws + 18 * MB);
    ushort_t* Wvb  = (ushort_t*)(ws + 20 * MB);
    ushort_t* QKb  = (ushort_t*)(ws + 32 * MB);
    ushort_t* Vt   = (ushort_t*)(ws + 64 * MB);
    ushort_t* Sc   = (ushort_t*)(ws);
    float* outp = out;

    cg::grid_group grid = cg::this_grid();
    const int gb = blockIdx.x;
    const int GS = gridDim.x;

    // phase 0: cast (5632 units)
    for (int u = gb; u < 5632; u += GS)
        cast_unit(u, x, Wq, Wk, Wv, Xb, Wqkb, Wkb, Wvb);
    grid.sync();

    // phase 1: proj (1024 units) + Vt (512 units)
    for (int u = gb; u < 1536; u += GS) {
        int bx, by, bz;
        if (u < 1024) {
            remapC<16, 64, 1, 8, 16>(u, bx, by, bz);
            gemm_unit<ushort_t, 1>(As, Bs, rs, Xb, Wqkb, bq, bk,
                                   QKb, 16, 1024, 1024, 2048, 1.0f,
                                   by * 128, bx * 128);
        } else {
            remapC<64, 8, 1, 16, 4>(u - 1024, bx, by, bz);
            gemm_unit<ushort_t, 2>(As, Bs, rs, Wvb, Xb, bv, nullptr,
                                   Vt, 16, 1024, 1024, 8192, 1.0f,
                                   by * 128, bx * 128);
        }
        __syncthreads();
    }
    grid.sync();

    // phase 2: Sc = exp(Q K^T / 32) (1024 units)
    for (int u = gb; u < 1024; u += GS) {
        int bx, by, bz;
        remapC<16, 16, 4, 8, 16>(u, bx, by, bz);
        const size_t zo = (size_t)bz * 2048 * 2048;
        gemm_unit<ushort_t, 3>(As, Bs, rs, QKb + zo, QKb + 1024 + zo,
                               nullptr, nullptr,
                               Sc + zo, 16, 2048, 2048, 2048, 0.03125f,
                               by * 128, bx * 128);
        __syncthreads();
    }
    grid.sync();

    // phase 3: out = (Sc Vt^T) / rowsum (512 units)
    for (int u = gb; u < 512; u += GS) {
        int bx, by, bz;
        remapC<8, 16, 4, 8, 8>(u, bx, by, bz);
        gemm_unit<float, 4>(As, Bs, rs,
                            Sc + (size_t)bz * 2048 * 2048,
                            Vt + (size_t)bz * 2048,
                            nullptr, nullptr,
                            outp + (size_t)bz * 2048 * 1024,
                            32, 2048, 8192, 1024, 1.0f,
                            by * 128, bx * 128);
        __syncthreads();
    }
}

// ---------------------------------------------------------------------------
// Fallback path (R14): separate dispatches reusing gemm_unit.
// ---------------------------------------------------------------------------
template <typename OT, int EPI, int CX, int CY>
__global__ __launch_bounds__(256, 2) void gemm_db(
    const ushort_t* __restrict__ A, const ushort_t* __restrict__ B,
    OT* __restrict__ C, int NT, int lda, int ldb, int ldc, float scale,
    long long aOffZ, long long bOffZ, long long cOffZ)
{
    __shared__ __align__(16) ushort_t As[2][8192];
    __shared__ __align__(16) ushort_t Bs[2][8192];
    __shared__ float rs[128];

    const int GX  = gridDim.x, GY = gridDim.y, GZ = gridDim.z;
    const int bid = blockIdx.x + GX * (blockIdx.y + GY * blockIdx.z);
    const int xcd = bid & 7, jj = bid >> 3;
    const int CZ  = (GX * GY * GZ) / (8 * CX * CY);
    const int NCX = GX / CX, NCY = GY / CY;
    const int cx  = xcd % NCX, ct = xcd / NCX;
    const int cy  = ct % NCY, cz = ct / NCY;
    const int bx  = cx * CX + (jj % CX);
    const int by  = cy * CY + ((jj / CX) % CY);
    const int bz  = cz * CZ + jj / (CX * CY);

    gemm_unit<OT, EPI>(As, Bs, rs,
                       A + (size_t)bz * aOffZ, B + (size_t)bz * bOffZ,
                       nullptr, nullptr,
                       C + (size_t)bz * cOffZ, NT, lda, ldb, ldc, scale,
                       by * 128, bx * 128);
}

__global__ __launch_bounds__(256, 2) void gemm_mrg(
    const ushort_t* __restrict__ Xb, const ushort_t* __restrict__ Wqkb,
    const ushort_t* __restrict__ Wvb,
    const float* __restrict__ bq, const float* __restrict__ bk,
    const float* __restrict__ bv,
    ushort_t* __restrict__ QKb, ushort_t* __restrict__ Vtp)
{
    __shared__ __align__(16) ushort_t As[2][8192];
    __shared__ __align__(16) ushort_t Bs[2][8192];
    __shared__ float rs[128];

    int bx, by, bz;
    if (blockIdx.x < 1024) {
        remapC<16, 64, 1, 8, 16>((int)blockIdx.x, bx, by, bz);
        gemm_unit<ushort_t, 1>(As, Bs, rs, Xb, Wqkb, bq, bk,
                               QKb, 16, 1024, 1024, 2048, 1.0f,
                               by * 128, bx * 128);
    } else {
        remapC<64, 8, 1, 16, 4>((int)blockIdx.x - 1024, bx, by, bz);
        gemm_unit<ushort_t, 2>(As, Bs, rs, Wvb, Xb, bv, nullptr,
                               Vtp, 16, 1024, 1024, 8192, 1.0f,
                               by * 128, bx * 128);
    }
}

__global__ __launch_bounds__(256) void cvt_all(
    const float* __restrict__ x,  const float* __restrict__ wq,
    const float* __restrict__ wk, const float* __restrict__ wv,
    ushort_t* __restrict__ xb,  ushort_t* __restrict__ wqb,
    ushort_t* __restrict__ wkb, ushort_t* __restrict__ wvb)
{
    cast_unit((int)blockIdx.x, x, wq, wk, wv, xb, wqb, wkb, wvb);
}

extern "C" void kernel_launch(void* const* d_in, const int* in_sizes, int n_in,
                              void* d_out, int out_size, void* d_ws, size_t ws_size,
                              hipStream_t stream)
{
    const float* x  = (const float*)d_in[0];
    const float* Wq = (const float*)d_in[1];
    const float* bq = (const float*)d_in[2];
    const float* Wk = (const float*)d_in[3];
    const float* bk = (const float*)d_in[4];
    const float* Wv = (const float*)d_in[5];
    const float* bv = (const float*)d_in[6];
    float* out = (float*)d_out;
    char* ws = (char*)d_ws;

    // primary: cooperative mega-kernel (512 blocks = 2/CU)
    int nb = 0;
    hipError_t qe = hipOccupancyMaxActiveBlocksPerMultiprocessor(
        &nb, reinterpret_cast<const void*>(mega), 256, 0);
    if (qe == hipSuccess && nb >= 2) {
        void* args[] = { (void*)&x, (void*)&Wq, (void*)&bq, (void*)&Wk,
                         (void*)&bk, (void*)&Wv, (void*)&bv, (void*)&out,
                         (void*)&ws };
        hipError_t le = hipLaunchCooperativeKernel(
            reinterpret_cast<const void*>(mega), dim3(512), dim3(256),
            args, 0, stream);
        if (le == hipSuccess) return;
    }

    // fallback: R14 4-dispatch path (identical unit body)
    const size_t MB = 1ull << 20;
    ushort_t* Xb   = (ushort_t*)(ws);
    ushort_t* Wqkb = (ushort_t*)(ws + 16 * MB);
    ushort_t* Wvb  = (ushort_t*)(ws + 20 * MB);
    ushort_t* QKb  = (ushort_t*)(ws + 32 * MB);
    ushort_t* Vt   = (ushort_t*)(ws + 64 * MB);
    ushort_t* Sc   = (ushort_t*)(ws);

    cvt_all<<<dim3(5632), dim3(256), 0, stream>>>(
        x, Wq, Wk, Wv, Xb, Wqkb, (ushort_t*)(ws + 18 * MB), Wvb);

    gemm_mrg<<<dim3(1536), dim3(256), 0, stream>>>(
        Xb, Wqkb, Wvb, bq, bk, bv, QKb, Vt);

    gemm_db<ushort_t, 3, 8, 16><<<dim3(16, 16, 4), dim3(256), 0, stream>>>(
        QKb, QKb + 1024, Sc, 16, 2048, 2048, 2048,
        0.03125f, 2048ll * 2048, 2048ll * 2048, 2048ll * 2048);

    gemm_db<float, 4, 8, 8><<<dim3(8, 16, 4), dim3(256), 0, stream>>>(
        Sc, Vt, out, 32, 2048, 8192, 1024, 1.0f,
        2048ll * 2048, 2048ll, 2048ll * 1024);
}

// Round 12
// 217.460 us; speedup vs baseline: 1.1474x; 1.0064x over previous
//
#include <hip/hip_runtime.h>
#include <hip/hip_cooperative_groups.h>
#include <cstdint>
#include <cstddef>

namespace cg = cooperative_groups;

// FeatureAttention: x[4,2048,1024] fp32; Q=xWq^T+bq, K=xWk^T+bk, V=xWv^T+bv;
// out = softmax(QK^T/32) V.  bf16 MFMA pipeline.
//
// R16 = R15 (coop mega-kernel, 512 blocks = 2/CU; proven 219us vs 235) with
// the scores->PV grid.sync replaced by per-panel dataflow flags:
//   sc[bz*16+by] counts finished scores tiles of row-panel (by,bz); target 16.
//   scores unit: __syncthreads (drains stores) + release atomicAdd (agent
//   scope -> L2 writeback). PV unit: spin acquire-load (agent scope -> L1+L2
//   invalidate, also evicts stale Xb-era lines aliased with Sc) then sync.
// Two grid.syncs remain: cast->proj (all-to-all weights) and proj->scores
// (Sc region overwrites Xb, which phase-1 still reads).
// Deadlock-free: unit order per block = scores,scores,PV; deps acyclic; all
// blocks co-resident (cooperative launch).
//
// Workspace (80 MB):
//   [0,16M)  Xb    [16,20) Wqkb  [20,22) Wvb   [22M +256B) sc counters
//   [32,64M) QKb   [8192][2048]: Q cols 0-1023, K cols 1024-2047
//   [64,80M) Vt    (V transposed [1024][8192])
//   [0,32M)  Sc    (exp(scores) bf16, overwrites Xb after sync #2)

typedef unsigned short ushort_t;
typedef __attribute__((ext_vector_type(8))) short short8;
typedef __attribute__((ext_vector_type(4))) float f32x4;

#define AS1 __attribute__((address_space(1)))
#define AS3 __attribute__((address_space(3)))

__device__ __forceinline__ ushort_t f2bf(float f) {
    unsigned int u = __float_as_uint(f);
    u += 0x7FFFu + ((u >> 16) & 1u);
    return (ushort_t)(u >> 16);
}

// async global->LDS, 16B/lane; lds dest = wave-uniform base + lane*16
__device__ __forceinline__ void async_ld16(const void* g, unsigned lds_off) {
    __builtin_amdgcn_global_load_lds((const AS1 void*)(uintptr_t)g,
                                     (AS3 void*)(uintptr_t)lds_off,
                                     16, 0, 0);
}

// panel dataflow: release-arrive / acquire-wait (device scope, cross-XCD)
__device__ __forceinline__ void panel_arrive(int* c) {
    __syncthreads();                 // drains every wave's stores (vmcnt 0)
    if (threadIdx.x == 0)
        __hip_atomic_fetch_add(c, 1, __ATOMIC_RELEASE,
                               __HIP_MEMORY_SCOPE_AGENT);
}
__device__ __forceinline__ void panel_wait(int* c, int tgt) {
    if (threadIdx.x == 0) {
        while (__hip_atomic_load(c, __ATOMIC_ACQUIRE,
                                 __HIP_MEMORY_SCOPE_AGENT) < tgt)
            __builtin_amdgcn_s_sleep(8);
    }
    __syncthreads();
}

// bijective XCD-chunked remap (XCD = id%8), compile-time geometry
template <int GX, int GY, int GZ, int CX, int CY>
__device__ __forceinline__ void remapC(int id, int& bx, int& by, int& bz) {
    constexpr int CZ  = (GX * GY * GZ) / (8 * CX * CY);
    constexpr int NCX = GX / CX, NCY = GY / CY;
    const int xcd = id & 7, jj = id >> 3;
    const int cx = xcd % NCX, ct = xcd / NCX;
    const int cy = ct % NCY, cz = ct / NCY;
    bx = cx * CX + (jj % CX);
    by = cy * CY + ((jj / CX) % CY);
    bz = cz * CZ + jj / (CX * CY);
}

// ---------------------------------------------------------------------------
// gemm_unit: one 128x128 output tile, BK=64 issue-early double-buffer,
// 4 waves 2x2.  C[m*ldc+n] = epi( scale * sum_k A[m*lda+k] * B[n*ldb+k] )
// EPI: 1 +bias(n): n<1024 ? b0[n] : b1[n-1024] | 2 +b0[m] | 3 exp(v)
//      4 v / rowsum(A row)  (rowsum via ones-MFMA, C/D row layout)
// Swizzle (P=8): 16B chunk c of row r at slot (c+r)&7 on the staging source.
// ---------------------------------------------------------------------------
template <typename OT, int EPI>
__device__ __forceinline__ void gemm_unit(
    ushort_t (&As)[2][8192], ushort_t (&Bs)[2][8192], float (&rs)[128],
    const ushort_t* __restrict__ A, const ushort_t* __restrict__ B,
    const float* __restrict__ b0, const float* __restrict__ b1,
    OT* __restrict__ C, int NT, int lda, int ldb, int ldc, float scale,
    int m0, int n0)
{
    constexpr int BK = 64;
    const int tid  = threadIdx.x;
    const int wave = tid >> 6;
    const int lane = tid & 63;
    const int wm = (wave >> 1) * 64;
    const int wn = (wave & 1) * 64;

    const unsigned lw  = (unsigned)(wave << 10);
    const unsigned aL0 = (unsigned)(uintptr_t)&As[0][0] + lw;
    const unsigned aL1 = (unsigned)(uintptr_t)&As[1][0] + lw;
    const unsigned bL0 = (unsigned)(uintptr_t)&Bs[0][0] + lw;
    const unsigned bL1 = (unsigned)(uintptr_t)&Bs[1][0] + lw;

    const int srow = wave * 8 + (lane >> 3);
    const int cd   = ((lane & 7) - srow) & 7;
    const ushort_t* gA = A + (size_t)(m0 + srow) * lda + cd * 8;
    const ushort_t* gB = B + (size_t)(n0 + srow) * ldb + cd * 8;

    auto stageT = [&](int t, unsigned la, unsigned lb) {
        const ushort_t* pA = gA + (size_t)t * BK;
        const ushort_t* pB = gB + (size_t)t * BK;
#pragma unroll
        for (int c = 0; c < 4; ++c) {
            async_ld16(pA + (size_t)(c * 32) * lda, la + c * 4096);
            async_ld16(pB + (size_t)(c * 32) * ldb, lb + c * 4096);
        }
    };

    const int frow = lane & 15;
    const int fg   = lane >> 4;

    f32x4 acc[4][4] = {};
    f32x4 rsm[4] = {};
    const short8 ones = { (short)0x3F80, (short)0x3F80, (short)0x3F80,
                          (short)0x3F80, (short)0x3F80, (short)0x3F80,
                          (short)0x3F80, (short)0x3F80 };

    auto computeT = [&](const ushort_t* Aw, const ushort_t* Bw) {
#pragma unroll
        for (int t2 = 0; t2 < 2; ++t2) {
            const int pa = (((t2 << 2) + fg + frow) & 7) << 3;
            short8 af[4], bf[4];
#pragma unroll
            for (int i = 0; i < 4; ++i)
                af[i] = *(const short8*)&Aw[(wm + i * 16 + frow) * BK + pa];
            if (EPI == 4 && wn == 0) {   // rowsum via matrix pipe
#pragma unroll
                for (int i = 0; i < 4; ++i)
                    rsm[i] = __builtin_amdgcn_mfma_f32_16x16x32_bf16(
                        af[i], ones, rsm[i], 0, 0, 0);
            }
#pragma unroll
            for (int j = 0; j < 4; ++j)
                bf[j] = *(const short8*)&Bw[(wn + j * 16 + frow) * BK + pa];
#pragma unroll
            for (int i = 0; i < 4; ++i)
#pragma unroll
                for (int j = 0; j < 4; ++j)
                    acc[i][j] = __builtin_amdgcn_mfma_f32_16x16x32_bf16(
                        af[i], bf[j], acc[i][j], 0, 0, 0);
        }
    };

    const ushort_t* A0 = &As[0][0];
    const ushort_t* A1 = &As[1][0];
    const ushort_t* B0 = &Bs[0][0];
    const ushort_t* B1 = &Bs[1][0];

    stageT(0, aL0, bL0);
    __syncthreads();

    int t = 0;
    for (; t + 2 < NT; t += 2) {
        stageT(t + 1, aL1, bL1);   // issued early: hidden under compute
        computeT(A0, B0);
        __syncthreads();
        stageT(t + 2, aL0, bL0);
        computeT(A1, B1);
        __syncthreads();
    }
    stageT(NT - 1, aL1, bL1);
    computeT(A0, B0);
    __syncthreads();
    computeT(A1, B1);

    const int r0 = fg << 2;
    const int c0 = lane & 15;

    if (EPI == 4) {
        if (wn == 0 && c0 == 0) {   // lanes 0,16,32,48 hold rows r0..r0+3
#pragma unroll
            for (int i = 0; i < 4; ++i)
#pragma unroll
                for (int r = 0; r < 4; ++r)
                    rs[wm + i * 16 + r0 + r] = rsm[i][r];
        }
        __syncthreads();
    }

    // C/D layout: lane l reg r -> row (l>>4)*4+r, col l&15
#pragma unroll
    for (int i = 0; i < 4; ++i) {
        float bm[4];
        if (EPI == 2) {
#pragma unroll
            for (int r = 0; r < 4; ++r)
                bm[r] = b0[m0 + wm + i * 16 + r0 + r];
        }
        if (EPI == 4) {
#pragma unroll
            for (int r = 0; r < 4; ++r)
                bm[r] = 1.0f / rs[wm + i * 16 + r0 + r];
        }
#pragma unroll
        for (int j = 0; j < 4; ++j) {
            const int n = n0 + wn + j * 16 + c0;
            float bn = 0.f;
            if (EPI == 1) bn = (n < 1024) ? b0[n] : b1[n - 1024];
#pragma unroll
            for (int r = 0; r < 4; ++r) {
                const int m = m0 + wm + i * 16 + r0 + r;
                float v = acc[i][j][r] * scale;
                if (EPI == 1) v += bn;
                if (EPI == 2) v += bm[r];
                if (EPI == 3) v = __expf(v);
                if (EPI == 4) v *= bm[r];
                if constexpr (sizeof(OT) == 2)
                    C[(size_t)m * ldc + n] = f2bf(v);
                else
                    C[(size_t)m * ldc + n] = v;
            }
        }
    }
}

// cast unit u: 2048 fp32 -> bf16 (256 threads x 8)
__device__ __forceinline__ void cast_unit(
    int u, const float* x, const float* Wq, const float* Wk, const float* Wv,
    ushort_t* Xb, ushort_t* Wqkb, ushort_t* Wkb, ushort_t* Wvb)
{
    const float* src; ushort_t* dst; size_t base;
    if (u < 4096)      { src = x;  dst = Xb;   base = (size_t)u * 2048; }
    else if (u < 4608) { src = Wq; dst = Wqkb; base = (size_t)(u - 4096) * 2048; }
    else if (u < 5120) { src = Wk; dst = Wkb;  base = (size_t)(u - 4608) * 2048; }
    else               { src = Wv; dst = Wvb;  base = (size_t)(u - 5120) * 2048; }
    const size_t i = base + threadIdx.x * 8;
    const f32x4 a = *(const f32x4*)(src + i);
    const f32x4 c = *(const f32x4*)(src + i + 4);
    short8 o;
    o[0] = (short)f2bf(a[0]); o[1] = (short)f2bf(a[1]);
    o[2] = (short)f2bf(a[2]); o[3] = (short)f2bf(a[3]);
    o[4] = (short)f2bf(c[0]); o[5] = (short)f2bf(c[1]);
    o[6] = (short)f2bf(c[2]); o[7] = (short)f2bf(c[3]);
    *(short8*)(dst + i) = o;
}

// ---------------------------------------------------------------------------
// mega: the whole op in one cooperative kernel.
// ---------------------------------------------------------------------------
__global__ __launch_bounds__(256, 2) void mega(
    const float* __restrict__ x,
    const float* __restrict__ Wq, const float* __restrict__ bq,
    const float* __restrict__ Wk, const float* __restrict__ bk,
    const float* __restrict__ Wv, const float* __restrict__ bv,
    float* __restrict__ out, char* __restrict__ ws)
{
    __shared__ __align__(16) ushort_t As[2][8192];
    __shared__ __align__(16) ushort_t Bs[2][8192];
    __shared__ float rs[128];

    const size_t MB = 1ull << 20;
    ushort_t* Xb   = (ushort_t*)(ws);
    ushort_t* Wqkb = (ushort_t*)(ws + 16 * MB);
    ushort_t* Wkb  = (ushort_t*)(ws + 18 * MB);
    ushort_t* Wvb  = (ushort_t*)(ws + 20 * MB);
    int*      scnt = (int*)(ws + 22 * MB);       // 64 panel counters
    ushort_t* QKb  = (ushort_t*)(ws + 32 * MB);
    ushort_t* Vt   = (ushort_t*)(ws + 64 * MB);
    ushort_t* Sc   = (ushort_t*)(ws);
    float* outp = out;

    cg::grid_group grid = cg::this_grid();
    const int gb = blockIdx.x;
    const int GS = gridDim.x;

    // phase 0: cast (5632 units) + zero panel counters
    if (gb == 0 && threadIdx.x < 64) scnt[threadIdx.x] = 0;
    for (int u = gb; u < 5632; u += GS)
        cast_unit(u, x, Wq, Wk, Wv, Xb, Wqkb, Wkb, Wvb);
    grid.sync();

    // phase 1: proj (1024 units) + Vt (512 units)
    for (int u = gb; u < 1536; u += GS) {
        int bx, by, bz;
        if (u < 1024) {
            remapC<16, 64, 1, 8, 16>(u, bx, by, bz);
            gemm_unit<ushort_t, 1>(As, Bs, rs, Xb, Wqkb, bq, bk,
                                   QKb, 16, 1024, 1024, 2048, 1.0f,
                                   by * 128, bx * 128);
        } else {
            remapC<64, 8, 1, 16, 4>(u - 1024, bx, by, bz);
            gemm_unit<ushort_t, 2>(As, Bs, rs, Wvb, Xb, bv, nullptr,
                                   Vt, 16, 1024, 1024, 8192, 1.0f,
                                   by * 128, bx * 128);
        }
        __syncthreads();
    }
    grid.sync();   // required: Sc overwrites Xb, phase 1 still reads Xb

    // phase 2: Sc = exp(Q K^T / 32) (1024 units); release per panel
    for (int u = gb; u < 1024; u += GS) {
        int bx, by, bz;
        remapC<16, 16, 4, 8, 16>(u, bx, by, bz);
        const size_t zo = (size_t)bz * 2048 * 2048;
        gemm_unit<ushort_t, 3>(As, Bs, rs, QKb + zo, QKb + 1024 + zo,
                               nullptr, nullptr,
                               Sc + zo, 16, 2048, 2048, 2048, 0.03125f,
                               by * 128, bx * 128);
        panel_arrive(&scnt[bz * 16 + by]);   // includes __syncthreads
    }

    // phase 3 (no grid.sync): PV waits on its Sc row-panel only
    for (int u = gb; u < 512; u += GS) {
        int bx, by, bz;
        remapC<8, 16, 4, 8, 8>(u, bx, by, bz);
        panel_wait(&scnt[bz * 16 + by], 16); // acquire: invalidates L1/L2
        gemm_unit<float, 4>(As, Bs, rs,
                            Sc + (size_t)bz * 2048 * 2048,
                            Vt + (size_t)bz * 2048,
                            nullptr, nullptr,
                            outp + (size_t)bz * 2048 * 1024,
                            32, 2048, 8192, 1024, 1.0f,
                            by * 128, bx * 128);
        __syncthreads();
    }
}

// ---------------------------------------------------------------------------
// Fallback path (R14): separate dispatches reusing gemm_unit.
// ---------------------------------------------------------------------------
template <typename OT, int EPI, int CX, int CY>
__global__ __launch_bounds__(256, 2) void gemm_db(
    const ushort_t* __restrict__ A, const ushort_t* __restrict__ B,
    OT* __restrict__ C, int NT, int lda, int ldb, int ldc, float scale,
    long long aOffZ, long long bOffZ, long long cOffZ)
{
    __shared__ __align__(16) ushort_t As[2][8192];
    __shared__ __align__(16) ushort_t Bs[2][8192];
    __shared__ float rs[128];

    const int GX  = gridDim.x, GY = gridDim.y, GZ = gridDim.z;
    const int bid = blockIdx.x + GX * (blockIdx.y + GY * blockIdx.z);
    const int xcd = bid & 7, jj = bid >> 3;
    const int CZ  = (GX * GY * GZ) / (8 * CX * CY);
    const int NCX = GX / CX, NCY = GY / CY;
    const int cx  = xcd % NCX, ct = xcd / NCX;
    const int cy  = ct % NCY, cz = ct / NCY;
    const int bx  = cx * CX + (jj % CX);
    const int by  = cy * CY + ((jj / CX) % CY);
    const int bz  = cz * CZ + jj / (CX * CY);

    gemm_unit<OT, EPI>(As, Bs, rs,
                       A + (size_t)bz * aOffZ, B + (size_t)bz * bOffZ,
                       nullptr, nullptr,
                       C + (size_t)bz * cOffZ, NT, lda, ldb, ldc, scale,
                       by * 128, bx * 128);
}

__global__ __launch_bounds__(256, 2) void gemm_mrg(
    const ushort_t* __restrict__ Xb, const ushort_t* __restrict__ Wqkb,
    const ushort_t* __restrict__ Wvb,
    const float* __restrict__ bq, const float* __restrict__ bk,
    const float* __restrict__ bv,
    ushort_t* __restrict__ QKb, ushort_t* __restrict__ Vtp)
{
    __shared__ __align__(16) ushort_t As[2][8192];
    __shared__ __align__(16) ushort_t Bs[2][8192];
    __shared__ float rs[128];

    int bx, by, bz;
    if (blockIdx.x < 1024) {
        remapC<16, 64, 1, 8, 16>((int)blockIdx.x, bx, by, bz);
        gemm_unit<ushort_t, 1>(As, Bs, rs, Xb, Wqkb, bq, bk,
                               QKb, 16, 1024, 1024, 2048, 1.0f,
                               by * 128, bx * 128);
    } else {
        remapC<64, 8, 1, 16, 4>((int)blockIdx.x - 1024, bx, by, bz);
        gemm_unit<ushort_t, 2>(As, Bs, rs, Wvb, Xb, bv, nullptr,
                               Vtp, 16, 1024, 1024, 8192, 1.0f,
                               by * 128, bx * 128);
    }
}

__global__ __launch_bounds__(256) void cvt_all(
    const float* __restrict__ x,  const float* __restrict__ wq,
    const float* __restrict__ wk, const float* __restrict__ wv,
    ushort_t* __restrict__ xb,  ushort_t* __restrict__ wqb,
    ushort_t* __restrict__ wkb, ushort_t* __restrict__ wvb)
{
    cast_unit((int)blockIdx.x, x, wq, wk, wv, xb, wqb, wkb, wvb);
}

extern "C" void kernel_launch(void* const* d_in, const int* in_sizes, int n_in,
                              void* d_out, int out_size, void* d_ws, size_t ws_size,
                              hipStream_t stream)
{
    const float* x  = (const float*)d_in[0];
    const float* Wq = (const float*)d_in[1];
    const float* bq = (const float*)d_in[2];
    const float* Wk = (const float*)d_in[3];
    const float* bk = (const float*)d_in[4];
    const float* Wv = (const float*)d_in[5];
    const float* bv = (const float*)d_in[6];
    float* out = (float*)d_out;
    char* ws = (char*)d_ws;

    // primary: cooperative mega-kernel (512 blocks = 2/CU)
    int nb = 0;
    hipError_t qe = hipOccupancyMaxActiveBlocksPerMultiprocessor(
        &nb, reinterpret_cast<const void*>(mega), 256, 0);
    if (qe == hipSuccess && nb >= 2) {
        void* args[] = { (void*)&x, (void*)&Wq, (void*)&bq, (void*)&Wk,
                         (void*)&bk, (void*)&Wv, (void*)&bv, (void*)&out,
                         (void*)&ws };
        hipError_t le = hipLaunchCooperativeKernel(
            reinterpret_cast<const void*>(mega), dim3(512), dim3(256),
            args, 0, stream);
        if (le == hipSuccess) return;
    }

    // fallback: R14 4-dispatch path (identical unit body)
    const size_t MB = 1ull << 20;
    ushort_t* Xb   = (ushort_t*)(ws);
    ushort_t* Wqkb = (ushort_t*)(ws + 16 * MB);
    ushort_t* Wvb  = (ushort_t*)(ws + 20 * MB);
    ushort_t* QKb  = (ushort_t*)(ws + 32 * MB);
    ushort_t* Vt   = (ushort_t*)(ws + 64 * MB);
    ushort_t* Sc   = (ushort_t*)(ws);

    cvt_all<<<dim3(5632), dim3(256), 0, stream>>>(
        x, Wq, Wk, Wv, Xb, Wqkb, (ushort_t*)(ws + 18 * MB), Wvb);

    gemm_mrg<<<dim3(1536), dim3(256), 0, stream>>>(
        Xb, Wqkb, Wvb, bq, bk, bv, QKb, Vt);

    gemm_db<ushort_t, 3, 8, 16><<<dim3(16, 16, 4), dim3(256), 0, stream>>>(
        QKb, QKb + 1024, Sc, 16, 2048, 2048, 2048,
        0.03125f, 2048ll * 2048, 2048ll * 2048, 2048ll * 2048);

    gemm_db<float, 4, 8, 8><<<dim3(8, 16, 4), dim3(256), 0, stream>>>(
        Sc, Vt, out, 32, 2048, 8192, 1024, 1.0f,
        2048ll * 2048, 2048ll, 2048ll * 1024);
}

// Round 13
// 213.152 us; speedup vs baseline: 1.1706x; 1.0202x over previous
//
#include <hip/hip_runtime.h>
#include <hip/hip_cooperative_groups.h>
#include <cstdint>
#include <cstddef>

namespace cg = cooperative_groups;

// FeatureAttention: x[4,2048,1024] fp32; Q=xWq^T+bq, K=xWk^T+bk, V=xWv^T+bv;
// out = softmax(QK^T/32) V.  bf16 MFMA pipeline.
//
// R17: ws_size is 256 MiB (R16 rocprof: harness poison-fill = 262144 KB), so
// Sc gets its own region (no Xb aliasing). This removes the need for the
// proj->scores grid.sync: the whole proj/Vt -> scores -> PV chain now runs on
// R16's hardware-proven panel dataflow (release atomicAdd / acquire spin).
// One grid.sync remains (cast -> GEMMs). Each block takes ONE acquire per
// phase (waits all its deps upfront) to preserve XCD-L2 locality.
// Gate: ws_size >= 128 MiB, else exact R16 path (MODE 0); non-coop fallback
// (R14 4-dispatch) if cooperative launch unavailable.
//
// BIG layout (MB):  Xb[0,16) Wqkb[16,20) Wvb[20,22) QKb[32,64) Vt[64,80)
//                   Sc[80,112)  counters@120 (qk 128 | vt 32 | sc 64 ints)
// SMALL layout: R16's aliased 80 MB layout (Sc overwrites Xb, 2 grid.syncs).

typedef unsigned short ushort_t;
typedef __attribute__((ext_vector_type(8))) short short8;
typedef __attribute__((ext_vector_type(4))) float f32x4;

#define AS1 __attribute__((address_space(1)))
#define AS3 __attribute__((address_space(3)))

__device__ __forceinline__ ushort_t f2bf(float f) {
    unsigned int u = __float_as_uint(f);
    u += 0x7FFFu + ((u >> 16) & 1u);
    return (ushort_t)(u >> 16);
}

// async global->LDS, 16B/lane; lds dest = wave-uniform base + lane*16
__device__ __forceinline__ void async_ld16(const void* g, unsigned lds_off) {
    __builtin_amdgcn_global_load_lds((const AS1 void*)(uintptr_t)g,
                                     (AS3 void*)(uintptr_t)lds_off,
                                     16, 0, 0);
}

// panel dataflow (R16-proven): release-arrive / acquire-wait, agent scope
__device__ __forceinline__ void panel_arrive(int* c) {
    __syncthreads();                 // drains every wave's stores
    if (threadIdx.x == 0)
        __hip_atomic_fetch_add(c, 1, __ATOMIC_RELEASE,
                               __HIP_MEMORY_SCOPE_AGENT);
}
__device__ __forceinline__ void spin1(int* c, int tgt) {
    while (__hip_atomic_load(c, __ATOMIC_ACQUIRE,
                             __HIP_MEMORY_SCOPE_AGENT) < tgt)
        __builtin_amdgcn_s_sleep(8);
}
__device__ __forceinline__ void panel_wait1(int* c, int t) {
    if (threadIdx.x == 0) spin1(c, t);
    __syncthreads();
}

// bijective XCD-chunked remap (XCD = id%8), compile-time geometry
template <int GX, int GY, int GZ, int CX, int CY>
__device__ __forceinline__ void remapC(int id, int& bx, int& by, int& bz) {
    constexpr int CZ  = (GX * GY * GZ) / (8 * CX * CY);
    constexpr int NCX = GX / CX, NCY = GY / CY;
    const int xcd = id & 7, jj = id >> 3;
    const int cx = xcd % NCX, ct = xcd / NCX;
    const int cy = ct % NCY, cz = ct / NCY;
    bx = cx * CX + (jj % CX);
    by = cy * CY + ((jj / CX) % CY);
    bz = cz * CZ + jj / (CX * CY);
}

// ---------------------------------------------------------------------------
// gemm_unit: one 128x128 output tile, BK=64 issue-early double-buffer,
// 4 waves 2x2.  C[m*ldc+n] = epi( scale * sum_k A[m*lda+k] * B[n*ldb+k] )
// EPI: 1 +bias(n): n<1024 ? b0[n] : b1[n-1024] | 2 +b0[m] | 3 exp(v)
//      4 v / rowsum(A row)  (rowsum via ones-MFMA, C/D row layout)
// Swizzle (P=8): 16B chunk c of row r at slot (c+r)&7 on the staging source.
// ---------------------------------------------------------------------------
template <typename OT, int EPI>
__device__ __forceinline__ void gemm_unit(
    ushort_t (&As)[2][8192], ushort_t (&Bs)[2][8192], float (&rs)[128],
    const ushort_t* __restrict__ A, const ushort_t* __restrict__ B,
    const float* __restrict__ b0, const float* __restrict__ b1,
    OT* __restrict__ C, int NT, int lda, int ldb, int ldc, float scale,
    int m0, int n0)
{
    constexpr int BK = 64;
    const int tid  = threadIdx.x;
    const int wave = tid >> 6;
    const int lane = tid & 63;
    const int wm = (wave >> 1) * 64;
    const int wn = (wave & 1) * 64;

    const unsigned lw  = (unsigned)(wave << 10);
    const unsigned aL0 = (unsigned)(uintptr_t)&As[0][0] + lw;
    const unsigned aL1 = (unsigned)(uintptr_t)&As[1][0] + lw;
    const unsigned bL0 = (unsigned)(uintptr_t)&Bs[0][0] + lw;
    const unsigned bL1 = (unsigned)(uintptr_t)&Bs[1][0] + lw;

    const int srow = wave * 8 + (lane >> 3);
    const int cd   = ((lane & 7) - srow) & 7;
    const ushort_t* gA = A + (size_t)(m0 + srow) * lda + cd * 8;
    const ushort_t* gB = B + (size_t)(n0 + srow) * ldb + cd * 8;

    auto stageT = [&](int t, unsigned la, unsigned lb) {
        const ushort_t* pA = gA + (size_t)t * BK;
        const ushort_t* pB = gB + (size_t)t * BK;
#pragma unroll
        for (int c = 0; c < 4; ++c) {
            async_ld16(pA + (size_t)(c * 32) * lda, la + c * 4096);
            async_ld16(pB + (size_t)(c * 32) * ldb, lb + c * 4096);
        }
    };

    const int frow = lane & 15;
    const int fg   = lane >> 4;

    f32x4 acc[4][4] = {};
    f32x4 rsm[4] = {};
    const short8 ones = { (short)0x3F80, (short)0x3F80, (short)0x3F80,
                          (short)0x3F80, (short)0x3F80, (short)0x3F80,
                          (short)0x3F80, (short)0x3F80 };

    auto computeT = [&](const ushort_t* Aw, const ushort_t* Bw) {
#pragma unroll
        for (int t2 = 0; t2 < 2; ++t2) {
            const int pa = (((t2 << 2) + fg + frow) & 7) << 3;
            short8 af[4], bf[4];
#pragma unroll
            for (int i = 0; i < 4; ++i)
                af[i] = *(const short8*)&Aw[(wm + i * 16 + frow) * BK + pa];
            if (EPI == 4 && wn == 0) {   // rowsum via matrix pipe
#pragma unroll
                for (int i = 0; i < 4; ++i)
                    rsm[i] = __builtin_amdgcn_mfma_f32_16x16x32_bf16(
                        af[i], ones, rsm[i], 0, 0, 0);
            }
#pragma unroll
            for (int j = 0; j < 4; ++j)
                bf[j] = *(const short8*)&Bw[(wn + j * 16 + frow) * BK + pa];
#pragma unroll
            for (int i = 0; i < 4; ++i)
#pragma unroll
                for (int j = 0; j < 4; ++j)
                    acc[i][j] = __builtin_amdgcn_mfma_f32_16x16x32_bf16(
                        af[i], bf[j], acc[i][j], 0, 0, 0);
        }
    };

    const ushort_t* A0 = &As[0][0];
    const ushort_t* A1 = &As[1][0];
    const ushort_t* B0 = &Bs[0][0];
    const ushort_t* B1 = &Bs[1][0];

    stageT(0, aL0, bL0);
    __syncthreads();

    int t = 0;
    for (; t + 2 < NT; t += 2) {
        stageT(t + 1, aL1, bL1);   // issued early: hidden under compute
        computeT(A0, B0);
        __syncthreads();
        stageT(t + 2, aL0, bL0);
        computeT(A1, B1);
        __syncthreads();
    }
    stageT(NT - 1, aL1, bL1);
    computeT(A0, B0);
    __syncthreads();
    computeT(A1, B1);

    const int r0 = fg << 2;
    const int c0 = lane & 15;

    if (EPI == 4) {
        if (wn == 0 && c0 == 0) {   // lanes 0,16,32,48 hold rows r0..r0+3
#pragma unroll
            for (int i = 0; i < 4; ++i)
#pragma unroll
                for (int r = 0; r < 4; ++r)
                    rs[wm + i * 16 + r0 + r] = rsm[i][r];
        }
        __syncthreads();
    }

    // C/D layout: lane l reg r -> row (l>>4)*4+r, col l&15
#pragma unroll
    for (int i = 0; i < 4; ++i) {
        float bm[4];
        if (EPI == 2) {
#pragma unroll
            for (int r = 0; r < 4; ++r)
                bm[r] = b0[m0 + wm + i * 16 + r0 + r];
        }
        if (EPI == 4) {
#pragma unroll
            for (int r = 0; r < 4; ++r)
                bm[r] = 1.0f / rs[wm + i * 16 + r0 + r];
        }
#pragma unroll
        for (int j = 0; j < 4; ++j) {
            const int n = n0 + wn + j * 16 + c0;
            float bn = 0.f;
            if (EPI == 1) bn = (n < 1024) ? b0[n] : b1[n - 1024];
#pragma unroll
            for (int r = 0; r < 4; ++r) {
                const int m = m0 + wm + i * 16 + r0 + r;
                float v = acc[i][j][r] * scale;
                if (EPI == 1) v += bn;
                if (EPI == 2) v += bm[r];
                if (EPI == 3) v = __expf(v);
                if (EPI == 4) v *= bm[r];
                if constexpr (sizeof(OT) == 2)
                    C[(size_t)m * ldc + n] = f2bf(v);
                else
                    C[(size_t)m * ldc + n] = v;
            }
        }
    }
}

// cast unit u: 2048 fp32 -> bf16 (256 threads x 8)
__device__ __forceinline__ void cast_unit(
    int u, const float* x, const float* Wq, const float* Wk, const float* Wv,
    ushort_t* Xb, ushort_t* Wqkb, ushort_t* Wkb, ushort_t* Wvb)
{
    const float* src; ushort_t* dst; size_t base;
    if (u < 4096)      { src = x;  dst = Xb;   base = (size_t)u * 2048; }
    else if (u < 4608) { src = Wq; dst = Wqkb; base = (size_t)(u - 4096) * 2048; }
    else if (u < 5120) { src = Wk; dst = Wkb;  base = (size_t)(u - 4608) * 2048; }
    else               { src = Wv; dst = Wvb;  base = (size_t)(u - 5120) * 2048; }
    const size_t i = base + threadIdx.x * 8;
    const f32x4 a = *(const f32x4*)(src + i);
    const f32x4 c = *(const f32x4*)(src + i + 4);
    short8 o;
    o[0] = (short)f2bf(a[0]); o[1] = (short)f2bf(a[1]);
    o[2] = (short)f2bf(a[2]); o[3] = (short)f2bf(a[3]);
    o[4] = (short)f2bf(c[0]); o[5] = (short)f2bf(c[1]);
    o[6] = (short)f2bf(c[2]); o[7] = (short)f2bf(c[3]);
    *(short8*)(dst + i) = o;
}

// ---------------------------------------------------------------------------
// mega<MODE>: MODE 1 = BIG (non-aliased Sc, 1 grid.sync + full dataflow)
//             MODE 0 = SMALL (R16 exact: aliased Sc, 2 grid.syncs + sc flow)
// ---------------------------------------------------------------------------
template <int MODE>
__global__ __launch_bounds__(256, 2) void mega(
    const float* __restrict__ x,
    const float* __restrict__ Wq, const float* __restrict__ bq,
    const float* __restrict__ Wk, const float* __restrict__ bk,
    const float* __restrict__ Wv, const float* __restrict__ bv,
    float* __restrict__ out, char* __restrict__ ws)
{
    __shared__ __align__(16) ushort_t As[2][8192];
    __shared__ __align__(16) ushort_t Bs[2][8192];
    __shared__ float rs[128];

    const size_t MB = 1ull << 20;
    ushort_t* Xb   = (ushort_t*)(ws);
    ushort_t* Wqkb = (ushort_t*)(ws + 16 * MB);
    ushort_t* Wkb  = (ushort_t*)(ws + 18 * MB);
    ushort_t* Wvb  = (ushort_t*)(ws + 20 * MB);
    ushort_t* QKb  = (ushort_t*)(ws + 32 * MB);
    ushort_t* Vt   = (ushort_t*)(ws + 64 * MB);
    ushort_t* Sc   = (MODE == 1) ? (ushort_t*)(ws + 80 * MB)
                                 : (ushort_t*)(ws);
    int* cnt = (MODE == 1) ? (int*)(ws + 120 * MB) : (int*)(ws + 22 * MB);
    int* qkc = cnt;            // 128: proj panels (by*2 + isK), target 8
    int* vtc = cnt + 128;      // 32: vt[by*4+bz], target 16
    int* scc = (MODE == 1) ? cnt + 160 : cnt;  // 64: sc[bz*16+by], target 16
    float* outp = out;

    cg::grid_group grid = cg::this_grid();
    const int gb = blockIdx.x;
    const int GS = gridDim.x;

    // phase 0: cast (5632 units) + zero counters
    if (gb == 0 && threadIdx.x < 224) cnt[threadIdx.x] = 0;
    for (int u = gb; u < 5632; u += GS)
        cast_unit(u, x, Wq, Wk, Wv, Xb, Wqkb, Wkb, Wvb);
    grid.sync();

    // phase 1: proj (1024 units) + Vt (512 units)
    for (int u = gb; u < 1536; u += GS) {
        int bx, by, bz;
        if (u < 1024) {
            remapC<16, 64, 1, 8, 16>(u, bx, by, bz);
            gemm_unit<ushort_t, 1>(As, Bs, rs, Xb, Wqkb, bq, bk,
                                   QKb, 16, 1024, 1024, 2048, 1.0f,
                                   by * 128, bx * 128);
            if (MODE == 1) panel_arrive(&qkc[by * 2 + (bx >= 8)]);
            else __syncthreads();
        } else {
            remapC<64, 8, 1, 16, 4>(u - 1024, bx, by, bz);
            gemm_unit<ushort_t, 2>(As, Bs, rs, Wvb, Xb, bv, nullptr,
                                   Vt, 16, 1024, 1024, 8192, 1.0f,
                                   by * 128, bx * 128);
            if (MODE == 1) panel_arrive(&vtc[by * 4 + (bx >> 4)]);
            else __syncthreads();
        }
    }
    if (MODE == 0) grid.sync();   // SMALL: Sc aliases Xb

    // phase 2: Sc = exp(Q K^T / 32) (1024 units = 2 per block)
    {
        int bx0, by0, bz0, bx1, by1, bz1;
        remapC<16, 16, 4, 8, 16>(gb, bx0, by0, bz0);
        remapC<16, 16, 4, 8, 16>(gb + 512, bx1, by1, bz1);
        if (MODE == 1) {          // single acquire for all 4 deps
            if (threadIdx.x == 0) {
                spin1(&qkc[(bz0 * 16 + by0) * 2], 8);
                spin1(&qkc[(bz0 * 16 + bx0) * 2 + 1], 8);
                spin1(&qkc[(bz1 * 16 + by1) * 2], 8);
                spin1(&qkc[(bz1 * 16 + bx1) * 2 + 1], 8);
            }
            __syncthreads();
        }
        const size_t zo0 = (size_t)bz0 * 2048 * 2048;
        gemm_unit<ushort_t, 3>(As, Bs, rs, QKb + zo0, QKb + 1024 + zo0,
                               nullptr, nullptr,
                               Sc + zo0, 16, 2048, 2048, 2048, 0.03125f,
                               by0 * 128, bx0 * 128);
        panel_arrive(&scc[bz0 * 16 + by0]);
        const size_t zo1 = (size_t)bz1 * 2048 * 2048;
        gemm_unit<ushort_t, 3>(As, Bs, rs, QKb + zo1, QKb + 1024 + zo1,
                               nullptr, nullptr,
                               Sc + zo1, 16, 2048, 2048, 2048, 0.03125f,
                               by1 * 128, bx1 * 128);
        panel_arrive(&scc[bz1 * 16 + by1]);
    }

    // phase 3: PV (512 units = 1 per block); waits Sc panel (+Vt panel in BIG)
    {
        int bx, by, bz;
        remapC<8, 16, 4, 8, 8>(gb, bx, by, bz);
        if (threadIdx.x == 0) {
            spin1(&scc[bz * 16 + by], 16);
            if (MODE == 1) spin1(&vtc[bx * 4 + bz], 16);
        }
        __syncthreads();
        gemm_unit<float, 4>(As, Bs, rs,
                            Sc + (size_t)bz * 2048 * 2048,
                            Vt + (size_t)bz * 2048,
                            nullptr, nullptr,
                            outp + (size_t)bz * 2048 * 1024,
                            32, 2048, 8192, 1024, 1.0f,
                            by * 128, bx * 128);
    }
}

// ---------------------------------------------------------------------------
// Fallback path (R14): separate dispatches reusing gemm_unit.
// ---------------------------------------------------------------------------
template <typename OT, int EPI, int CX, int CY>
__global__ __launch_bounds__(256, 2) void gemm_db(
    const ushort_t* __restrict__ A, const ushort_t* __restrict__ B,
    OT* __restrict__ C, int NT, int lda, int ldb, int ldc, float scale,
    long long aOffZ, long long bOffZ, long long cOffZ)
{
    __shared__ __align__(16) ushort_t As[2][8192];
    __shared__ __align__(16) ushort_t Bs[2][8192];
    __shared__ float rs[128];

    const int GX  = gridDim.x, GY = gridDim.y, GZ = gridDim.z;
    const int bid = blockIdx.x + GX * (blockIdx.y + GY * blockIdx.z);
    const int xcd = bid & 7, jj = bid >> 3;
    const int CZ  = (GX * GY * GZ) / (8 * CX * CY);
    const int NCX = GX / CX, NCY = GY / CY;
    const int cx  = xcd % NCX, ct = xcd / NCX;
    const int cy  = ct % NCY, cz = ct / NCY;
    const int bx  = cx * CX + (jj % CX);
    const int by  = cy * CY + ((jj / CX) % CY);
    const int bz  = cz * CZ + jj / (CX * CY);

    gemm_unit<OT, EPI>(As, Bs, rs,
                       A + (size_t)bz * aOffZ, B + (size_t)bz * bOffZ,
                       nullptr, nullptr,
                       C + (size_t)bz * cOffZ, NT, lda, ldb, ldc, scale,
                       by * 128, bx * 128);
}

__global__ __launch_bounds__(256, 2) void gemm_mrg(
    const ushort_t* __restrict__ Xb, const ushort_t* __restrict__ Wqkb,
    const ushort_t* __restrict__ Wvb,
    const float* __restrict__ bq, const float* __restrict__ bk,
    const float* __restrict__ bv,
    ushort_t* __restrict__ QKb, ushort_t* __restrict__ Vtp)
{
    __shared__ __align__(16) ushort_t As[2][8192];
    __shared__ __align__(16) ushort_t Bs[2][8192];
    __shared__ float rs[128];

    int bx, by, bz;
    if (blockIdx.x < 1024) {
        remapC<16, 64, 1, 8, 16>((int)blockIdx.x, bx, by, bz);
        gemm_unit<ushort_t, 1>(As, Bs, rs, Xb, Wqkb, bq, bk,
                               QKb, 16, 1024, 1024, 2048, 1.0f,
                               by * 128, bx * 128);
    } else {
        remapC<64, 8, 1, 16, 4>((int)blockIdx.x - 1024, bx, by, bz);
        gemm_unit<ushort_t, 2>(As, Bs, rs, Wvb, Xb, bv, nullptr,
                               Vtp, 16, 1024, 1024, 8192, 1.0f,
                               by * 128, bx * 128);
    }
}

__global__ __launch_bounds__(256) void cvt_all(
    const float* __restrict__ x,  const float* __restrict__ wq,
    const float* __restrict__ wk, const float* __restrict__ wv,
    ushort_t* __restrict__ xb,  ushort_t* __restrict__ wqb,
    ushort_t* __restrict__ wkb, ushort_t* __restrict__ wvb)
{
    cast_unit((int)blockIdx.x, x, wq, wk, wv, xb, wqb, wkb, wvb);
}

extern "C" void kernel_launch(void* const* d_in, const int* in_sizes, int n_in,
                              void* d_out, int out_size, void* d_ws, size_t ws_size,
                              hipStream_t stream)
{
    const float* x  = (const float*)d_in[0];
    const float* Wq = (const float*)d_in[1];
    const float* bq = (const float*)d_in[2];
    const float* Wk = (const float*)d_in[3];
    const float* bk = (const float*)d_in[4];
    const float* Wv = (const float*)d_in[5];
    const float* bv = (const float*)d_in[6];
    float* out = (float*)d_out;
    char* ws = (char*)d_ws;

    const bool big = ws_size >= (128ull << 20);
    const void* fn = big ? reinterpret_cast<const void*>(mega<1>)
                         : reinterpret_cast<const void*>(mega<0>);

    int nb = 0;
    hipError_t qe = hipOccupancyMaxActiveBlocksPerMultiprocessor(
        &nb, fn, 256, 0);
    if (qe == hipSuccess && nb >= 2) {
        void* args[] = { (void*)&x, (void*)&Wq, (void*)&bq, (void*)&Wk,
                         (void*)&bk, (void*)&Wv, (void*)&bv, (void*)&out,
                         (void*)&ws };
        hipError_t le = hipLaunchCooperativeKernel(
            fn, dim3(512), dim3(256), args, 0, stream);
        if (le == hipSuccess) return;
    }

    // fallback: R14 4-dispatch path (identical unit body, aliased layout)
    const size_t MB = 1ull << 20;
    ushort_t* Xb   = (ushort_t*)(ws);
    ushort_t* Wqkb = (ushort_t*)(ws + 16 * MB);
    ushort_t* Wvb  = (ushort_t*)(ws + 20 * MB);
    ushort_t* QKb  = (ushort_t*)(ws + 32 * MB);
    ushort_t* Vt   = (ushort_t*)(ws + 64 * MB);
    ushort_t* Sc   = (ushort_t*)(ws);

    cvt_all<<<dim3(5632), dim3(256), 0, stream>>>(
        x, Wq, Wk, Wv, Xb, Wqkb, (ushort_t*)(ws + 18 * MB), Wvb);

    gemm_mrg<<<dim3(1536), dim3(256), 0, stream>>>(
        Xb, Wqkb, Wvb, bq, bk, bv, QKb, Vt);

    gemm_db<ushort_t, 3, 8, 16><<<dim3(16, 16, 4), dim3(256), 0, stream>>>(
        QKb, QKb + 1024, Sc, 16, 2048, 2048, 2048,
        0.03125f, 2048ll * 2048, 2048ll * 2048, 2048ll * 2048);

    gemm_db<float, 4, 8, 8><<<dim3(8, 16, 4), dim3(256), 0, stream>>>(
        Sc, Vt, out, 32, 2048, 8192, 1024, 1.0f,
        2048ll * 2048, 2048ll, 2048ll * 1024);
}